// Round 10
// baseline (518.530 us; speedup 1.0000x reference)
//
#include <hip/hip_runtime.h>
#include <math.h>

#define N_NODES 50000
#define N_EDGES 800000
#define IN_DIM 512
#define HID 128
#define HEADS 8
#define HEAD_DIM 16
#define N_LAYERS 3
#define N_CLASSES 8
#define LOG2E 1.4426950408889634f

typedef __attribute__((ext_vector_type(8))) short short8;
typedef __attribute__((ext_vector_type(4))) short short4v;
typedef __attribute__((ext_vector_type(4))) float f32x4;

__device__ inline unsigned short f2bf(float f) {
  unsigned u = __float_as_uint(f);
  u = (u + 0x7fffu + ((u >> 16) & 1u)) >> 16;
  return (unsigned short)u;
}
__device__ inline float bflo(unsigned u) { return __uint_as_float(u << 16); }
__device__ inline float bfhi(unsigned u) { return __uint_as_float(u & 0xffff0000u); }

// ---------------- prep: weight fp32->bf16 transpose + zero deg/cur ----------------
__global__ __launch_bounds__(256) void k_prep(
    const float* __restrict__ W_in, const float* __restrict__ Wc,
    const float* __restrict__ W1, const float* __restrict__ W2,
    const float* __restrict__ W3,
    unsigned short* __restrict__ Wt_in, unsigned short* __restrict__ Wt_c,
    unsigned short* __restrict__ W1t, unsigned short* __restrict__ W2t,
    unsigned short* __restrict__ W3t, int* __restrict__ degcur) {
  int i = blockIdx.x * blockDim.x + threadIdx.x;
  if (i < 2 * N_NODES) degcur[i] = 0;
  if (i < IN_DIM * HID) {                      // Wt_in[c][k]
    int c = i >> 9, k = i & 511;
    Wt_in[i] = f2bf(W_in[k * HID + c]);
  }
  if (i < N_LAYERS * HID * HID) {              // Wt_c[l][c][k]
    int l = i >> 14, r = i & 16383, c = r >> 7, k = r & 127;
    Wt_c[i] = f2bf(Wc[l * HID * HID + k * HID + c]);
  }
  if (i < 64 * 128) {                          // W1t[c][k]
    int c = i >> 7, k = i & 127;
    W1t[i] = f2bf(W1[k * 64 + c]);
  }
  if (i < 32 * 64) {                           // W2t[c][k]
    int c = i >> 6, k = i & 63;
    W2t[i] = f2bf(W2[k * 32 + c]);
  }
  if (i < 16 * 32) {                           // W3t[c][k], cols 8..15 zero-padded
    int c = i >> 5, k = i & 31;
    W3t[i] = (c < 8) ? f2bf(W3[k * N_CLASSES + c]) : 0;
  }
}

// ---------------- MFMA GEMM mainloop: C[64 x 128] += A_f32[64 x K] @ W_bf16t ----------------
template <int K>
__device__ inline void gemm_mainloop(const float* __restrict__ A, size_t row0,
                                     const unsigned short* __restrict__ Wt,
                                     unsigned short* lds_a, unsigned short* lds_b,
                                     f32x4 acc[8]) {
  const int tid = threadIdx.x;
  const int lane = tid & 63, wid = tid >> 6;
#pragma unroll
  for (int f = 0; f < 8; ++f)
#pragma unroll
    for (int j = 0; j < 4; ++j) acc[f][j] = 0.f;

  for (int kb = 0; kb < K; kb += 64) {
#pragma unroll
    for (int j = 0; j < 4; ++j) {
      int i = tid + j * 256;
      int r = i >> 4, kq = (i & 15) * 4;
      size_t rg = row0 + r;
      if (rg >= N_NODES) rg = N_NODES - 1;
      float4 v = *(const float4*)(A + rg * K + kb + kq);
      short4v b4;
      b4[0] = (short)f2bf(v.x); b4[1] = (short)f2bf(v.y);
      b4[2] = (short)f2bf(v.z); b4[3] = (short)f2bf(v.w);
      int idx = (r * 64 + kq) ^ ((r & 7) << 3);
      *(short4v*)&lds_a[idx] = b4;
    }
#pragma unroll
    for (int j = 0; j < 4; ++j) {
      int i = tid + j * 256;
      int c = i >> 3, kq = (i & 7) * 8;
      short8 w = *(const short8*)(Wt + (size_t)c * K + kb + kq);
      int idx = (c * 64 + kq) ^ ((c & 7) << 3);
      *(short8*)&lds_b[idx] = w;
    }
    __syncthreads();

    int arow = wid * 16 + (lane & 15);
    int kq8 = (lane >> 4) * 8;
    short8 a0 = *(short8*)&lds_a[(arow * 64 + kq8) ^ ((arow & 7) << 3)];
    short8 a1 = *(short8*)&lds_a[(arow * 64 + 32 + kq8) ^ ((arow & 7) << 3)];
#pragma unroll
    for (int f = 0; f < 8; ++f) {
      int c = f * 16 + (lane & 15);
      short8 b0 = *(short8*)&lds_b[(c * 64 + kq8) ^ ((c & 7) << 3)];
      short8 b1 = *(short8*)&lds_b[(c * 64 + 32 + kq8) ^ ((c & 7) << 3)];
      acc[f] = __builtin_amdgcn_mfma_f32_16x16x32_bf16(a0, b0, acc[f], 0, 0, 0);
      acc[f] = __builtin_amdgcn_mfma_f32_16x16x32_bf16(a1, b1, acc[f], 0, 0, 0);
    }
    __syncthreads();
  }
}

// ---------------- input projection GEMM + bias + LN + relu ----------------
__global__ __launch_bounds__(256) void k_gemm_in(
    const float* __restrict__ x, const unsigned short* __restrict__ Wt,
    const float* __restrict__ b, const float* __restrict__ g,
    const float* __restrict__ be, float* __restrict__ h0) {
  __shared__ unsigned short lds_a[64 * 64];
  __shared__ unsigned short lds_b[128 * 64];
  f32x4 acc[8];
  size_t row0 = (size_t)blockIdx.x * 64;
  gemm_mainloop<IN_DIM>(x, row0, Wt, lds_a, lds_b, acc);

  int lane = threadIdx.x & 63, wid = threadIdx.x >> 6;
  int cbase = lane & 15;
  float s[4] = {0.f, 0.f, 0.f, 0.f}, q[4] = {0.f, 0.f, 0.f, 0.f};
  float gg[8], bb[8];
#pragma unroll
  for (int f = 0; f < 8; ++f) {
    int c = f * 16 + cbase;
    float bias = b[c];
    gg[f] = g[c]; bb[f] = be[c];
#pragma unroll
    for (int j = 0; j < 4; ++j) {
      float v = acc[f][j] + bias;
      acc[f][j] = v;
      s[j] += v; q[j] += v * v;
    }
  }
#pragma unroll
  for (int off = 8; off >= 1; off >>= 1)
#pragma unroll
    for (int j = 0; j < 4; ++j) {
      s[j] += __shfl_xor(s[j], off);
      q[j] += __shfl_xor(q[j], off);
    }
#pragma unroll
  for (int j = 0; j < 4; ++j) {
    size_t row = row0 + wid * 16 + (lane >> 4) * 4 + j;
    if (row < N_NODES) {
      float mu = s[j] * (1.f / 128.f);
      float var = q[j] * (1.f / 128.f) - mu * mu;
      float rs = rsqrtf(var + 1e-5f);
#pragma unroll
      for (int f = 0; f < 8; ++f) {
        float y = (acc[f][j] - mu) * rs * gg[f] + bb[f];
        h0[row * HID + f * 16 + cbase] = fmaxf(y, 0.f);
      }
    }
  }
}

// ---------------- GAT projection GEMM + hp blocked-bf16 store + es/ed ----------------
// hp_blk layout: [4][N][32] bf16 — channel c lives in block c>>5 at offset c&31.
__global__ __launch_bounds__(256) void k_gemm_gat(
    const float* __restrict__ h, const unsigned short* __restrict__ Wt,
    const float* __restrict__ asrc, const float* __restrict__ adst,
    unsigned short* __restrict__ hp_blk, float* __restrict__ es,
    float* __restrict__ ed) {
  __shared__ unsigned short lds_a[64 * 64];
  __shared__ unsigned short lds_b[128 * 64];
  f32x4 acc[8];
  size_t row0 = (size_t)blockIdx.x * 64;
  gemm_mainloop<HID>(h, row0, Wt, lds_a, lds_b, acc);

  int lane = threadIdx.x & 63, wid = threadIdx.x >> 6;
  int cbase = lane & 15;
#pragma unroll
  for (int f = 0; f < 8; ++f) {   // frag f == head f (cols f*16..f*16+15)
    float av = asrc[f * 16 + cbase], bv = adst[f * 16 + cbase];
    float eS[4], eD[4];
#pragma unroll
    for (int j = 0; j < 4; ++j) { eS[j] = acc[f][j] * av; eD[j] = acc[f][j] * bv; }
#pragma unroll
    for (int off = 8; off >= 1; off >>= 1)
#pragma unroll
      for (int j = 0; j < 4; ++j) {
        eS[j] += __shfl_xor(eS[j], off);
        eD[j] += __shfl_xor(eD[j], off);
      }
#pragma unroll
    for (int j = 0; j < 4; ++j) {
      size_t row = row0 + wid * 16 + (lane >> 4) * 4 + j;
      if (row < N_NODES) {
        // blocked store: blk = f>>1, offset (f&1)*16 + cbase
        hp_blk[((size_t)(f >> 1) * N_NODES + row) * 32 + (f & 1) * 16 + cbase] =
            f2bf(acc[f][j]);
        if (cbase == 0) {
          es[row * HEADS + f] = eS[j] * LOG2E;
          ed[row * HEADS + f] = eD[j] * LOG2E;
        }
      }
    }
  }
}

// ---------------- CSR build ----------------
__global__ void k_count(const int* __restrict__ dst, int* __restrict__ deg) {
  int e = blockIdx.x * blockDim.x + threadIdx.x;
  if (e < N_EDGES) atomicAdd(&deg[dst[e]], 1);
}

__global__ __launch_bounds__(1024) void k_scan(const int* __restrict__ deg,
                                               int* __restrict__ offs) {
  __shared__ int wsum[16];
  __shared__ int s_carry;
  int tid = threadIdx.x, lane = tid & 63, wid = tid >> 6;
  if (tid == 0) { s_carry = 0; offs[0] = 0; }
  __syncthreads();
  for (int base = 0; base < N_NODES; base += 8192) {
    int i0 = base + tid * 8;
    int v[8];
    int run = 0;
#pragma unroll
    for (int k = 0; k < 8; ++k) {
      int d = (i0 + k < N_NODES) ? deg[i0 + k] : 0;
      run += d; v[k] = run;
    }
    int ws = run;
#pragma unroll
    for (int off = 1; off < 64; off <<= 1) {
      int t = __shfl_up(ws, off);
      if (lane >= off) ws += t;
    }
    if (lane == 63) wsum[wid] = ws;
    __syncthreads();
    int carry = s_carry;
    int prefix = carry;
    for (int w = 0; w < wid; ++w) prefix += wsum[w];
    int excl = prefix + ws - run;
#pragma unroll
    for (int k = 0; k < 8; ++k)
      if (i0 + k < N_NODES) offs[i0 + k + 1] = excl + v[k];
    __syncthreads();
    if (tid == 0) {
      int tot = 0;
      for (int w = 0; w < 16; ++w) tot += wsum[w];
      s_carry = carry + tot;
    }
    __syncthreads();
  }
}

__global__ void k_scatter(const int* __restrict__ src, const int* __restrict__ dst,
                          const int* __restrict__ offs, int* __restrict__ cur,
                          int* __restrict__ col) {
  int e = blockIdx.x * blockDim.x + threadIdx.x;
  if (e < N_EDGES) {
    int d = dst[e];
    int pos = offs[d] + atomicAdd(&cur[d], 1);
    col[pos] = src[e];
  }
}

// ---------------- GAT aggregation: channel-blocked passes (L2-resident gathers) ----------
// Grid = 4 passes x ceil(N/4) blocks; pass p gathers only hp block p (3.2 MB -> fits XCD L2).
// Wave = one dst node. lane l: edge-group grp=l>>4 (4 edges in flight), li=l&15 ->
// channels 2li,2li+1 of the 32-block, head gh = 2*pass + (li>>3). Per-lane strided edge
// loop, no shuffles; cross-group combine via 2 shfl_xor at the end.
__global__ __launch_bounds__(256) void k_gat_agg(
    const unsigned short* __restrict__ hp_blk, const float* __restrict__ es,
    const float* __restrict__ ed, const int* __restrict__ offs,
    const int* __restrict__ col, float* __restrict__ vtmp) {
  const int NB4 = (N_NODES + 3) / 4;
  int bid = blockIdx.x;
  int pass = bid / NB4, nb = bid - pass * NB4;
  int lane = threadIdx.x & 63, wid = threadIdx.x >> 6;
  int n = nb * 4 + wid;
  if (n >= N_NODES) return;
  int grp = lane >> 4, li = lane & 15;
  int gh = 2 * pass + (li >> 3);
  const unsigned* hpu = (const unsigned*)hp_blk + (size_t)pass * N_NODES * 16;

  float edv = ed[(size_t)n * HEADS + gh];
  float den = 0.f, ax = 0.f, ay = 0.f;
  if (grp == 0) {                       // self-loop (counted once)
    float z0 = es[(size_t)n * HEADS + gh] + edv;
    z0 = fmaxf(z0, 0.2f * z0);
    float p0 = exp2f(z0);
    unsigned su = hpu[(size_t)n * 16 + li];
    den = p0; ax = p0 * bflo(su); ay = p0 * bfhi(su);
  }
  int s1 = offs[n + 1];
#pragma unroll 2
  for (int e = offs[n] + grp; e < s1; e += 4) {
    int se = col[e];
    float z = es[(size_t)se * HEADS + gh] + edv;
    z = fmaxf(z, 0.2f * z);             // leaky_relu (pre-scaled by log2e)
    float p = exp2f(z);
    unsigned hu = hpu[(size_t)se * 16 + li];
    den += p;
    ax = fmaf(p, bflo(hu), ax);
    ay = fmaf(p, bfhi(hu), ay);
  }
  // combine the 4 edge-groups (lanes li, li+16, li+32, li+48)
#pragma unroll
  for (int off = 16; off <= 32; off <<= 1) {
    den += __shfl_xor(den, off);
    ax  += __shfl_xor(ax, off);
    ay  += __shfl_xor(ay, off);
  }
  if (grp == 0) {
    float rden = 1.f / (den + 1e-16f);
    ((float2*)vtmp)[((size_t)pass * N_NODES + n) * 16 + li] =
        make_float2(ax * rden, ay * rden);
  }
}

// ---------------- bias + LN + relu + residual over blocked vtmp -> row-major h_out ----
__global__ __launch_bounds__(256) void k_ln_res(
    const float* __restrict__ vtmp, const float* __restrict__ bc,
    const float* __restrict__ gc, const float* __restrict__ bec,
    const float* __restrict__ h_res, float* __restrict__ h_out, int use_res) {
  int lane = threadIdx.x & 63;
  int n = blockIdx.x * 4 + (threadIdx.x >> 6);
  if (n >= N_NODES) return;
  int blk = lane >> 4, li = lane & 15;
  float2 v = ((const float2*)vtmp)[((size_t)blk * N_NODES + n) * 16 + li];
  int c0 = 2 * lane;                    // == 32*blk + 2*li
  float v0 = v.x + bc[c0], v1 = v.y + bc[c0 + 1];

  float s = v0 + v1, q = v0 * v0 + v1 * v1;
#pragma unroll
  for (int off = 32; off >= 1; off >>= 1) {
    s += __shfl_xor(s, off);
    q += __shfl_xor(q, off);
  }
  float mu = s * (1.f / 128.f);
  float var = q * (1.f / 128.f) - mu * mu;
  float rs = rsqrtf(var + 1e-5f);
  float y0 = fmaxf((v0 - mu) * rs * gc[c0] + bec[c0], 0.f);
  float y1 = fmaxf((v1 - mu) * rs * gc[c0 + 1] + bec[c0 + 1], 0.f);
  if (use_res) {
    float2 r = ((const float2*)h_res)[(size_t)n * 64 + lane];
    y0 += r.x; y1 += r.y;
  }
  ((float2*)h_out)[(size_t)n * 64 + lane] = make_float2(y0, y1);
}

// ---------------- classifier head: fused 3-stage MFMA MLP ----------------
__global__ __launch_bounds__(256) void k_head_mfma(
    const float* __restrict__ h,
    const unsigned short* __restrict__ W1t, const float* __restrict__ b1,
    const float* __restrict__ g1, const float* __restrict__ be1,
    const unsigned short* __restrict__ W2t, const float* __restrict__ b2,
    const float* __restrict__ g2, const float* __restrict__ be2,
    const unsigned short* __restrict__ W3t, const float* __restrict__ b3,
    float* __restrict__ out) {
  __shared__ unsigned short lds_a[64 * 128];
  __shared__ unsigned short lds_b1[64 * 128];
  __shared__ unsigned short lds_h1[64 * 64];
  __shared__ unsigned short lds_b2[32 * 64];
  __shared__ unsigned short lds_h2[64 * 32];
  __shared__ unsigned short lds_b3[16 * 32];
  int tid = threadIdx.x, lane = tid & 63, wid = tid >> 6;
  size_t row0 = (size_t)blockIdx.x * 64;

#pragma unroll
  for (int jj = 0; jj < 8; ++jj) {
    int i = tid + jj * 256;
    int r = i >> 5, kq = (i & 31) * 4;
    size_t rg = row0 + r;
    if (rg >= N_NODES) rg = N_NODES - 1;
    float4 v = *(const float4*)(h + rg * HID + kq);
    short4v b4;
    b4[0] = (short)f2bf(v.x); b4[1] = (short)f2bf(v.y);
    b4[2] = (short)f2bf(v.z); b4[3] = (short)f2bf(v.w);
    int idx = (r * 128 + kq) ^ ((r & 7) << 3);
    *(short4v*)&lds_a[idx] = b4;
  }
#pragma unroll
  for (int jj = 0; jj < 4; ++jj) {
    int i = tid + jj * 256;
    int c = i >> 4, kq = (i & 15) * 8;
    short8 w = *(const short8*)(W1t + c * 128 + kq);
    int idx = (c * 128 + kq) ^ ((c & 7) << 3);
    *(short8*)&lds_b1[idx] = w;
  }
  {
    int c = tid >> 3, kq = (tid & 7) * 8;
    if (c < 32) {
      short8 w = *(const short8*)(W2t + c * 64 + kq);
      int idx = (c * 64 + kq) ^ ((c & 7) << 3);
      *(short8*)&lds_b2[idx] = w;
    }
  }
  if (tid < 64) {
    int c = tid >> 2, kq = (tid & 3) * 8;
    short8 w = *(const short8*)(W3t + c * 32 + kq);
    int idx = (c * 32 + kq) ^ ((c & 3) << 3);
    *(short8*)&lds_b3[idx] = w;
  }
  __syncthreads();

  int arow = wid * 16 + (lane & 15);
  int kq8 = (lane >> 4) * 8;
  int cbase = lane & 15;

  // ---- stage 1: 128 -> 64 ----
  f32x4 acc1[4];
#pragma unroll
  for (int f = 0; f < 4; ++f)
#pragma unroll
    for (int j = 0; j < 4; ++j) acc1[f][j] = 0.f;
  {
    short8 a0 = *(short8*)&lds_a[(arow * 128 + kq8) ^ ((arow & 7) << 3)];
    short8 a1 = *(short8*)&lds_a[(arow * 128 + 32 + kq8) ^ ((arow & 7) << 3)];
    short8 a2 = *(short8*)&lds_a[(arow * 128 + 64 + kq8) ^ ((arow & 7) << 3)];
    short8 a3 = *(short8*)&lds_a[(arow * 128 + 96 + kq8) ^ ((arow & 7) << 3)];
#pragma unroll
    for (int f = 0; f < 4; ++f) {
      int c = f * 16 + cbase;
      short8 b0 = *(short8*)&lds_b1[(c * 128 + kq8) ^ ((c & 7) << 3)];
      short8 bb1 = *(short8*)&lds_b1[(c * 128 + 32 + kq8) ^ ((c & 7) << 3)];
      short8 b2v = *(short8*)&lds_b1[(c * 128 + 64 + kq8) ^ ((c & 7) << 3)];
      short8 b3v = *(short8*)&lds_b1[(c * 128 + 96 + kq8) ^ ((c & 7) << 3)];
      acc1[f] = __builtin_amdgcn_mfma_f32_16x16x32_bf16(a0, b0, acc1[f], 0, 0, 0);
      acc1[f] = __builtin_amdgcn_mfma_f32_16x16x32_bf16(a1, bb1, acc1[f], 0, 0, 0);
      acc1[f] = __builtin_amdgcn_mfma_f32_16x16x32_bf16(a2, b2v, acc1[f], 0, 0, 0);
      acc1[f] = __builtin_amdgcn_mfma_f32_16x16x32_bf16(a3, b3v, acc1[f], 0, 0, 0);
    }
  }
  {
    float s[4] = {0, 0, 0, 0}, q[4] = {0, 0, 0, 0};
#pragma unroll
    for (int f = 0; f < 4; ++f) {
      int c = f * 16 + cbase;
      float bias = b1[c];
#pragma unroll
      for (int j = 0; j < 4; ++j) {
        float v = acc1[f][j] + bias;
        acc1[f][j] = v;
        s[j] += v; q[j] += v * v;
      }
    }
#pragma unroll
    for (int off = 8; off >= 1; off >>= 1)
#pragma unroll
      for (int j = 0; j < 4; ++j) {
        s[j] += __shfl_xor(s[j], off);
        q[j] += __shfl_xor(q[j], off);
      }
#pragma unroll
    for (int j = 0; j < 4; ++j) {
      int row = wid * 16 + (lane >> 4) * 4 + j;
      float mu = s[j] * (1.f / 64.f);
      float var = q[j] * (1.f / 64.f) - mu * mu;
      float rs = rsqrtf(var + 1e-5f);
#pragma unroll
      for (int f = 0; f < 4; ++f) {
        int c = f * 16 + cbase;
        float y = fmaxf((acc1[f][j] - mu) * rs * g1[c] + be1[c], 0.f);
        lds_h1[(row * 64 + c) ^ ((row & 7) << 3)] = f2bf(y);
      }
    }
  }
  __syncthreads();

  // ---- stage 2: 64 -> 32 ----
  f32x4 acc2[2];
#pragma unroll
  for (int f = 0; f < 2; ++f)
#pragma unroll
    for (int j = 0; j < 4; ++j) acc2[f][j] = 0.f;
  {
    short8 a0 = *(short8*)&lds_h1[(arow * 64 + kq8) ^ ((arow & 7) << 3)];
    short8 a1 = *(short8*)&lds_h1[(arow * 64 + 32 + kq8) ^ ((arow & 7) << 3)];
#pragma unroll
    for (int f = 0; f < 2; ++f) {
      int c = f * 16 + cbase;
      short8 b0 = *(short8*)&lds_b2[(c * 64 + kq8) ^ ((c & 7) << 3)];
      short8 bb1 = *(short8*)&lds_b2[(c * 64 + 32 + kq8) ^ ((c & 7) << 3)];
      acc2[f] = __builtin_amdgcn_mfma_f32_16x16x32_bf16(a0, b0, acc2[f], 0, 0, 0);
      acc2[f] = __builtin_amdgcn_mfma_f32_16x16x32_bf16(a1, bb1, acc2[f], 0, 0, 0);
    }
  }
  {
    float s[4] = {0, 0, 0, 0}, q[4] = {0, 0, 0, 0};
#pragma unroll
    for (int f = 0; f < 2; ++f) {
      int c = f * 16 + cbase;
      float bias = b2[c];
#pragma unroll
      for (int j = 0; j < 4; ++j) {
        float v = acc2[f][j] + bias;
        acc2[f][j] = v;
        s[j] += v; q[j] += v * v;
      }
    }
#pragma unroll
    for (int off = 8; off >= 1; off >>= 1)
#pragma unroll
      for (int j = 0; j < 4; ++j) {
        s[j] += __shfl_xor(s[j], off);
        q[j] += __shfl_xor(q[j], off);
      }
#pragma unroll
    for (int j = 0; j < 4; ++j) {
      int row = wid * 16 + (lane >> 4) * 4 + j;
      float mu = s[j] * (1.f / 32.f);
      float var = q[j] * (1.f / 32.f) - mu * mu;
      float rs = rsqrtf(var + 1e-5f);
#pragma unroll
      for (int f = 0; f < 2; ++f) {
        int c = f * 16 + cbase;
        float y = fmaxf((acc2[f][j] - mu) * rs * g2[c] + be2[c], 0.f);
        lds_h2[(row * 32 + c) ^ ((row & 3) << 3)] = f2bf(y);
      }
    }
  }
  __syncthreads();

  // ---- stage 3: 32 -> 8 (cols padded to 16) ----
  f32x4 acc3;
#pragma unroll
  for (int j = 0; j < 4; ++j) acc3[j] = 0.f;
  {
    short8 a = *(short8*)&lds_h2[(arow * 32 + kq8) ^ ((arow & 3) << 3)];
    short8 b = *(short8*)&lds_b3[(cbase * 32 + kq8) ^ ((cbase & 3) << 3)];
    acc3 = __builtin_amdgcn_mfma_f32_16x16x32_bf16(a, b, acc3, 0, 0, 0);
  }
  if (cbase < N_CLASSES) {
    float bias = b3[cbase];
#pragma unroll
    for (int j = 0; j < 4; ++j) {
      size_t row = row0 + wid * 16 + (lane >> 4) * 4 + j;
      if (row < N_NODES) out[row * N_CLASSES + cbase] = acc3[j] + bias;
    }
  }
}

// ---------------- launch ----------------
extern "C" void kernel_launch(void* const* d_in, const int* in_sizes, int n_in,
                              void* d_out, int out_size, void* d_ws, size_t ws_size,
                              hipStream_t stream) {
  const float* x     = (const float*)d_in[0];
  const int*   esrc  = (const int*)d_in[1];
  const int*   edst  = (const int*)d_in[2];
  const float* W_in  = (const float*)d_in[3];
  const float* b_in  = (const float*)d_in[4];
  const float* g_in  = (const float*)d_in[5];
  const float* be_in = (const float*)d_in[6];
  const float* Wc    = (const float*)d_in[7];
  const float* a_src = (const float*)d_in[8];
  const float* a_dst = (const float*)d_in[9];
  const float* bc    = (const float*)d_in[10];
  const float* gc    = (const float*)d_in[11];
  const float* bec   = (const float*)d_in[12];
  const float* W1    = (const float*)d_in[13];
  const float* b1    = (const float*)d_in[14];
  const float* g1    = (const float*)d_in[15];
  const float* be1   = (const float*)d_in[16];
  const float* W2    = (const float*)d_in[17];
  const float* b2    = (const float*)d_in[18];
  const float* g2    = (const float*)d_in[19];
  const float* be2   = (const float*)d_in[20];
  const float* W3    = (const float*)d_in[21];
  const float* b3    = (const float*)d_in[22];

  float* ws = (float*)d_ws;
  const size_t NH = (size_t)N_NODES * HID;
  float* hA = ws;
  float* hB = hA + NH;
  float* vtmp = hB + NH;                       // [4][N][32] fp32
  float* es = vtmp + NH;
  float* ed = es + (size_t)N_NODES * HEADS;
  unsigned short* hp_blk = (unsigned short*)(ed + (size_t)N_NODES * HEADS);
  int* deg  = (int*)(hp_blk + NH);
  int* cur  = deg + N_NODES;
  int* offs = cur + N_NODES;
  int* col  = offs + N_NODES + 1;
  uintptr_t wp = (uintptr_t)(col + N_EDGES);
  wp = (wp + 15) & ~(uintptr_t)15;
  unsigned short* Wt_in = (unsigned short*)wp;
  unsigned short* Wt_c  = Wt_in + (size_t)IN_DIM * HID;
  unsigned short* W1t   = Wt_c + (size_t)N_LAYERS * HID * HID;
  unsigned short* W2t   = W1t + 64 * 128;
  unsigned short* W3t   = W2t + 32 * 64;

  // weights -> bf16 transposed + zero deg/cur (merged)
  k_prep<<<(2 * N_NODES + 255) / 256, 256, 0, stream>>>(
      W_in, Wc, W1, W2, W3, Wt_in, Wt_c, W1t, W2t, W3t, deg);

  // input projection + LN + relu (MFMA)
  k_gemm_in<<<(N_NODES + 63) / 64, 256, 0, stream>>>(x, Wt_in, b_in, g_in, be_in, hA);

  // CSR build (reused across all 3 layers)
  k_count<<<(N_EDGES + 255) / 256, 256, 0, stream>>>(edst, deg);
  k_scan<<<1, 1024, 0, stream>>>(deg, offs);
  k_scatter<<<(N_EDGES + 255) / 256, 256, 0, stream>>>(esrc, edst, offs, cur, col);

  const int NB4 = (N_NODES + 3) / 4;
  float* hcur = hA;
  float* hnext = hB;
  for (int l = 0; l < N_LAYERS; ++l) {
    k_gemm_gat<<<(N_NODES + 63) / 64, 256, 0, stream>>>(
        hcur, Wt_c + (size_t)l * HID * HID,
        a_src + (size_t)l * HEADS * HEAD_DIM, a_dst + (size_t)l * HEADS * HEAD_DIM,
        hp_blk, es, ed);
    k_gat_agg<<<4 * NB4, 256, 0, stream>>>(hp_blk, es, ed, offs, col, vtmp);
    k_ln_res<<<NB4, 256, 0, stream>>>(
        vtmp, bc + (size_t)l * HID, gc + (size_t)l * HID, bec + (size_t)l * HID,
        hcur, hnext, l > 0 ? 1 : 0);
    float* t = hcur; hcur = hnext; hnext = t;
  }

  k_head_mfma<<<(N_NODES + 63) / 64, 256, 0, stream>>>(
      hcur, W1t, b1, g1, be1, W2t, b2, g2, be2, W3t, b3, (float*)d_out);
}

// Round 11
// 516.861 us; speedup vs baseline: 1.0032x; 1.0032x over previous
//
#include <hip/hip_runtime.h>
#include <math.h>

#define N_NODES 50000
#define N_EDGES 800000
#define IN_DIM 512
#define HID 128
#define HEADS 8
#define HEAD_DIM 16
#define N_LAYERS 3
#define N_CLASSES 8
#define LOG2E 1.4426950408889634f
#define NRANGE 4
#define RANGE_SZ 12500

typedef __attribute__((ext_vector_type(8))) short short8;
typedef __attribute__((ext_vector_type(4))) short short4v;
typedef __attribute__((ext_vector_type(4))) float f32x4;

__device__ inline unsigned short f2bf(float f) {
  unsigned u = __float_as_uint(f);
  u = (u + 0x7fffu + ((u >> 16) & 1u)) >> 16;
  return (unsigned short)u;
}
__device__ inline float bflo(unsigned u) { return __uint_as_float(u << 16); }
__device__ inline float bfhi(unsigned u) { return __uint_as_float(u & 0xffff0000u); }

// ---------------- prep: weight fp32->bf16 transpose + zero deg2/cur2 ----------------
__global__ __launch_bounds__(256) void k_prep(
    const float* __restrict__ W_in, const float* __restrict__ Wc,
    const float* __restrict__ W1, const float* __restrict__ W2,
    const float* __restrict__ W3,
    unsigned short* __restrict__ Wt_in, unsigned short* __restrict__ Wt_c,
    unsigned short* __restrict__ W1t, unsigned short* __restrict__ W2t,
    unsigned short* __restrict__ W3t, int* __restrict__ degcur) {
  int i = blockIdx.x * blockDim.x + threadIdx.x;
  if (i < 2 * NRANGE * N_NODES) degcur[i] = 0;   // deg2[4N] + cur2[4N]
  if (i < IN_DIM * HID) {                      // Wt_in[c][k]
    int c = i >> 9, k = i & 511;
    Wt_in[i] = f2bf(W_in[k * HID + c]);
  }
  if (i < N_LAYERS * HID * HID) {              // Wt_c[l][c][k]
    int l = i >> 14, r = i & 16383, c = r >> 7, k = r & 127;
    Wt_c[i] = f2bf(Wc[l * HID * HID + k * HID + c]);
  }
  if (i < 64 * 128) {                          // W1t[c][k]
    int c = i >> 7, k = i & 127;
    W1t[i] = f2bf(W1[k * 64 + c]);
  }
  if (i < 32 * 64) {                           // W2t[c][k]
    int c = i >> 6, k = i & 63;
    W2t[i] = f2bf(W2[k * 32 + c]);
  }
  if (i < 16 * 32) {                           // W3t[c][k], cols 8..15 zero-padded
    int c = i >> 5, k = i & 31;
    W3t[i] = (c < 8) ? f2bf(W3[k * N_CLASSES + c]) : 0;
  }
}

// ---------------- MFMA GEMM mainloop: C[64 x 128] += A_f32[64 x K] @ W_bf16t ----------------
template <int K>
__device__ inline void gemm_mainloop(const float* __restrict__ A, size_t row0,
                                     const unsigned short* __restrict__ Wt,
                                     unsigned short* lds_a, unsigned short* lds_b,
                                     f32x4 acc[8]) {
  const int tid = threadIdx.x;
  const int lane = tid & 63, wid = tid >> 6;
#pragma unroll
  for (int f = 0; f < 8; ++f)
#pragma unroll
    for (int j = 0; j < 4; ++j) acc[f][j] = 0.f;

  for (int kb = 0; kb < K; kb += 64) {
#pragma unroll
    for (int j = 0; j < 4; ++j) {
      int i = tid + j * 256;
      int r = i >> 4, kq = (i & 15) * 4;
      size_t rg = row0 + r;
      if (rg >= N_NODES) rg = N_NODES - 1;
      float4 v = *(const float4*)(A + rg * K + kb + kq);
      short4v b4;
      b4[0] = (short)f2bf(v.x); b4[1] = (short)f2bf(v.y);
      b4[2] = (short)f2bf(v.z); b4[3] = (short)f2bf(v.w);
      int idx = (r * 64 + kq) ^ ((r & 7) << 3);
      *(short4v*)&lds_a[idx] = b4;
    }
#pragma unroll
    for (int j = 0; j < 4; ++j) {
      int i = tid + j * 256;
      int c = i >> 3, kq = (i & 7) * 8;
      short8 w = *(const short8*)(Wt + (size_t)c * K + kb + kq);
      int idx = (c * 64 + kq) ^ ((c & 7) << 3);
      *(short8*)&lds_b[idx] = w;
    }
    __syncthreads();

    int arow = wid * 16 + (lane & 15);
    int kq8 = (lane >> 4) * 8;
    short8 a0 = *(short8*)&lds_a[(arow * 64 + kq8) ^ ((arow & 7) << 3)];
    short8 a1 = *(short8*)&lds_a[(arow * 64 + 32 + kq8) ^ ((arow & 7) << 3)];
#pragma unroll
    for (int f = 0; f < 8; ++f) {
      int c = f * 16 + (lane & 15);
      short8 b0 = *(short8*)&lds_b[(c * 64 + kq8) ^ ((c & 7) << 3)];
      short8 b1 = *(short8*)&lds_b[(c * 64 + 32 + kq8) ^ ((c & 7) << 3)];
      acc[f] = __builtin_amdgcn_mfma_f32_16x16x32_bf16(a0, b0, acc[f], 0, 0, 0);
      acc[f] = __builtin_amdgcn_mfma_f32_16x16x32_bf16(a1, b1, acc[f], 0, 0, 0);
    }
    __syncthreads();
  }
}

// ---------------- input projection GEMM + bias + LN + relu ----------------
__global__ __launch_bounds__(256) void k_gemm_in(
    const float* __restrict__ x, const unsigned short* __restrict__ Wt,
    const float* __restrict__ b, const float* __restrict__ g,
    const float* __restrict__ be, float* __restrict__ h0) {
  __shared__ unsigned short lds_a[64 * 64];
  __shared__ unsigned short lds_b[128 * 64];
  f32x4 acc[8];
  size_t row0 = (size_t)blockIdx.x * 64;
  gemm_mainloop<IN_DIM>(x, row0, Wt, lds_a, lds_b, acc);

  int lane = threadIdx.x & 63, wid = threadIdx.x >> 6;
  int cbase = lane & 15;
  float s[4] = {0.f, 0.f, 0.f, 0.f}, q[4] = {0.f, 0.f, 0.f, 0.f};
  float gg[8], bb[8];
#pragma unroll
  for (int f = 0; f < 8; ++f) {
    int c = f * 16 + cbase;
    float bias = b[c];
    gg[f] = g[c]; bb[f] = be[c];
#pragma unroll
    for (int j = 0; j < 4; ++j) {
      float v = acc[f][j] + bias;
      acc[f][j] = v;
      s[j] += v; q[j] += v * v;
    }
  }
#pragma unroll
  for (int off = 8; off >= 1; off >>= 1)
#pragma unroll
    for (int j = 0; j < 4; ++j) {
      s[j] += __shfl_xor(s[j], off);
      q[j] += __shfl_xor(q[j], off);
    }
#pragma unroll
  for (int j = 0; j < 4; ++j) {
    size_t row = row0 + wid * 16 + (lane >> 4) * 4 + j;
    if (row < N_NODES) {
      float mu = s[j] * (1.f / 128.f);
      float var = q[j] * (1.f / 128.f) - mu * mu;
      float rs = rsqrtf(var + 1e-5f);
#pragma unroll
      for (int f = 0; f < 8; ++f) {
        float y = (acc[f][j] - mu) * rs * gg[f] + bb[f];
        h0[row * HID + f * 16 + cbase] = fmaxf(y, 0.f);
      }
    }
  }
}

// ---------------- GAT projection GEMM + hp(bf16) store + es/ed (pre-scaled by log2e) ----------------
__global__ __launch_bounds__(256) void k_gemm_gat(
    const float* __restrict__ h, const unsigned short* __restrict__ Wt,
    const float* __restrict__ asrc, const float* __restrict__ adst,
    unsigned short* __restrict__ hp_bf, float* __restrict__ es,
    float* __restrict__ ed) {
  __shared__ unsigned short lds_a[64 * 64];
  __shared__ unsigned short lds_b[128 * 64];
  f32x4 acc[8];
  size_t row0 = (size_t)blockIdx.x * 64;
  gemm_mainloop<HID>(h, row0, Wt, lds_a, lds_b, acc);

  int lane = threadIdx.x & 63, wid = threadIdx.x >> 6;
  int cbase = lane & 15;
#pragma unroll
  for (int f = 0; f < 8; ++f) {   // frag f == head f (cols f*16..f*16+15)
    float av = asrc[f * 16 + cbase], bv = adst[f * 16 + cbase];
    float eS[4], eD[4];
#pragma unroll
    for (int j = 0; j < 4; ++j) { eS[j] = acc[f][j] * av; eD[j] = acc[f][j] * bv; }
#pragma unroll
    for (int off = 8; off >= 1; off >>= 1)
#pragma unroll
      for (int j = 0; j < 4; ++j) {
        eS[j] += __shfl_xor(eS[j], off);
        eD[j] += __shfl_xor(eD[j], off);
      }
#pragma unroll
    for (int j = 0; j < 4; ++j) {
      size_t row = row0 + wid * 16 + (lane >> 4) * 4 + j;
      if (row < N_NODES) {
        hp_bf[row * HID + f * 16 + cbase] = f2bf(acc[f][j]);
        if (cbase == 0) {
          es[row * HEADS + f] = eS[j] * LOG2E;
          ed[row * HEADS + f] = eD[j] * LOG2E;
        }
      }
    }
  }
}

// ---------------- CSR build (bucketed by src range for L2 locality) ----------------
// offs2 keyed [node][range]: node n's edges occupy [offs2[4n], offs2[4n+4]), grouped
// by src/12500 so concurrently-running agg waves gather from one 3.2MB hp slice.
__global__ void k_count(const int* __restrict__ src, const int* __restrict__ dst,
                        int* __restrict__ deg2) {
  int e = blockIdx.x * blockDim.x + threadIdx.x;
  if (e < N_EDGES) {
    int r = src[e] / RANGE_SZ;
    atomicAdd(&deg2[dst[e] * NRANGE + r], 1);
  }
}

__global__ __launch_bounds__(1024) void k_scan(const int* __restrict__ deg2,
                                               int* __restrict__ offs2) {
  const int NTOT = NRANGE * N_NODES;
  __shared__ int wsum[16];
  __shared__ int s_carry;
  int tid = threadIdx.x, lane = tid & 63, wid = tid >> 6;
  if (tid == 0) { s_carry = 0; offs2[0] = 0; }
  __syncthreads();
  for (int base = 0; base < NTOT; base += 8192) {
    int i0 = base + tid * 8;
    int v[8];
    int run = 0;
#pragma unroll
    for (int k = 0; k < 8; ++k) {
      int d = (i0 + k < NTOT) ? deg2[i0 + k] : 0;
      run += d; v[k] = run;
    }
    int ws = run;
#pragma unroll
    for (int off = 1; off < 64; off <<= 1) {
      int t = __shfl_up(ws, off);
      if (lane >= off) ws += t;
    }
    if (lane == 63) wsum[wid] = ws;
    __syncthreads();
    int carry = s_carry;
    int prefix = carry;
    for (int w = 0; w < wid; ++w) prefix += wsum[w];
    int excl = prefix + ws - run;
#pragma unroll
    for (int k = 0; k < 8; ++k)
      if (i0 + k < NTOT) offs2[i0 + k + 1] = excl + v[k];
    __syncthreads();
    if (tid == 0) {
      int tot = 0;
      for (int w = 0; w < 16; ++w) tot += wsum[w];
      s_carry = carry + tot;
    }
    __syncthreads();
  }
}

__global__ void k_scatter(const int* __restrict__ src, const int* __restrict__ dst,
                          const int* __restrict__ offs2, int* __restrict__ cur2,
                          int* __restrict__ col) {
  int e = blockIdx.x * blockDim.x + threadIdx.x;
  if (e < N_EDGES) {
    int s = src[e];
    int idx = dst[e] * NRANGE + s / RANGE_SZ;
    int pos = offs2[idx] + atomicAdd(&cur2[idx], 1);
    col[pos] = s;
  }
}

// ---------------- GAT aggregation: wave/node, 8-edge batched, 2-deep software pipeline ----
// Edge list per node is src-range-sorted -> concurrent waves hit an L2-resident hp slice.
__global__ __launch_bounds__(256) void k_gat_agg(
    const unsigned short* __restrict__ hp_bf, const float* __restrict__ es,
    const float* __restrict__ ed, const int* __restrict__ offs2,
    const int* __restrict__ col, const float* __restrict__ bc,
    const float* __restrict__ gc, const float* __restrict__ bec,
    const float* __restrict__ h_res, float* __restrict__ h_out, int use_res) {
  int lane = threadIdx.x & 63;
  int n = blockIdx.x * 4 + (threadIdx.x >> 6);
  if (n >= N_NODES) return;
  int head = lane >> 3;
  int sub = lane & 7;
  int hbase = head * 8;
  const unsigned* hpu = (const unsigned*)hp_bf;  // 2 bf16 channels per uint

  float edv = ed[(size_t)n * HEADS + head];
  float z0 = es[(size_t)n * HEADS + head] + edv;
  z0 = fmaxf(z0, 0.2f * z0);            // leaky_relu (pre-scaled by log2e)
  float p0 = exp2f(z0);                 // self-loop weight
  unsigned su = hpu[(size_t)n * 64 + lane];

  float den0 = p0, ax0 = p0 * bflo(su), ay0 = p0 * bfhi(su);
  float den1 = 0.f, ax1 = 0.f, ay1 = 0.f;

  int s0 = offs2[n * NRANGE], s1 = offs2[n * NRANGE + NRANGE];
  int nb = (s1 - s0) >> 3;
  int base = s0;
  int se = 0;
  float p = 0.f;
  if (nb > 0) {                          // prologue: batch 0 logits
    se = col[base + sub];
    float z = es[(size_t)se * HEADS + head] + edv;
    z = fmaxf(z, 0.2f * z);
    p = exp2f(z);
  }
  for (int t = 0; t < nb; ++t) {
    int seN = 0;
    bool more = (t + 1 < nb);
    if (more) seN = col[base + 8 + sub]; // issue next col load first
#pragma unroll
    for (int k = 0; k < 8; k += 2) {     // current batch hp gathers + accumulate
      float pk0 = __shfl(p, hbase + k);
      float pk1 = __shfl(p, hbase + k + 1);
      int sk0 = __shfl(se, k);
      int sk1 = __shfl(se, k + 1);
      unsigned h0 = hpu[(size_t)sk0 * 64 + lane];
      unsigned h1 = hpu[(size_t)sk1 * 64 + lane];
      den0 += pk0;
      ax0 = fmaf(pk0, bflo(h0), ax0);
      ay0 = fmaf(pk0, bfhi(h0), ay0);
      den1 += pk1;
      ax1 = fmaf(pk1, bflo(h1), ax1);
      ay1 = fmaf(pk1, bfhi(h1), ay1);
    }
    if (more) {                          // next batch logits (overlapped with hp waits)
      float zN = es[(size_t)seN * HEADS + head] + edv;
      zN = fmaxf(zN, 0.2f * zN);
      p = exp2f(zN);
      se = seN;
    }
    base += 8;
  }
  int rem = s1 - base;
  if (rem > 0) {
    int e = base + (sub < rem ? sub : rem - 1);
    int set = col[e];
    float z = es[(size_t)set * HEADS + head] + edv;
    z = fmaxf(z, 0.2f * z);
    float pt = (sub < rem) ? exp2f(z) : 0.f;
    for (int k = 0; k < rem; ++k) {
      float pk = __shfl(pt, hbase + k);
      int sk = __shfl(set, k);
      unsigned hk = hpu[(size_t)sk * 64 + lane];
      den0 += pk;
      ax0 = fmaf(pk, bflo(hk), ax0);
      ay0 = fmaf(pk, bfhi(hk), ay0);
    }
  }
  float den = den0 + den1 + 1e-16f;
  float rden = 1.f / den;
  float v0 = (ax0 + ax1) * rden + bc[2 * lane];
  float v1 = (ay0 + ay1) * rden + bc[2 * lane + 1];

  float s = v0 + v1, q = v0 * v0 + v1 * v1;
#pragma unroll
  for (int off = 32; off >= 1; off >>= 1) {
    s += __shfl_xor(s, off);
    q += __shfl_xor(q, off);
  }
  float mu = s * (1.f / 128.f);
  float var = q * (1.f / 128.f) - mu * mu;
  float rs = rsqrtf(var + 1e-5f);
  float y0 = fmaxf((v0 - mu) * rs * gc[2 * lane] + bec[2 * lane], 0.f);
  float y1 = fmaxf((v1 - mu) * rs * gc[2 * lane + 1] + bec[2 * lane + 1], 0.f);
  if (use_res) {
    float2 r = ((const float2*)h_res)[(size_t)n * 64 + lane];
    y0 += r.x; y1 += r.y;
  }
  ((float2*)h_out)[(size_t)n * 64 + lane] = make_float2(y0, y1);
}

// ---------------- classifier head: fused 3-stage MFMA MLP ----------------
__global__ __launch_bounds__(256) void k_head_mfma(
    const float* __restrict__ h,
    const unsigned short* __restrict__ W1t, const float* __restrict__ b1,
    const float* __restrict__ g1, const float* __restrict__ be1,
    const unsigned short* __restrict__ W2t, const float* __restrict__ b2,
    const float* __restrict__ g2, const float* __restrict__ be2,
    const unsigned short* __restrict__ W3t, const float* __restrict__ b3,
    float* __restrict__ out) {
  __shared__ unsigned short lds_a[64 * 128];
  __shared__ unsigned short lds_b1[64 * 128];
  __shared__ unsigned short lds_h1[64 * 64];
  __shared__ unsigned short lds_b2[32 * 64];
  __shared__ unsigned short lds_h2[64 * 32];
  __shared__ unsigned short lds_b3[16 * 32];
  int tid = threadIdx.x, lane = tid & 63, wid = tid >> 6;
  size_t row0 = (size_t)blockIdx.x * 64;

#pragma unroll
  for (int jj = 0; jj < 8; ++jj) {
    int i = tid + jj * 256;
    int r = i >> 5, kq = (i & 31) * 4;
    size_t rg = row0 + r;
    if (rg >= N_NODES) rg = N_NODES - 1;
    float4 v = *(const float4*)(h + rg * HID + kq);
    short4v b4;
    b4[0] = (short)f2bf(v.x); b4[1] = (short)f2bf(v.y);
    b4[2] = (short)f2bf(v.z); b4[3] = (short)f2bf(v.w);
    int idx = (r * 128 + kq) ^ ((r & 7) << 3);
    *(short4v*)&lds_a[idx] = b4;
  }
#pragma unroll
  for (int jj = 0; jj < 4; ++jj) {
    int i = tid + jj * 256;
    int c = i >> 4, kq = (i & 15) * 8;
    short8 w = *(const short8*)(W1t + c * 128 + kq);
    int idx = (c * 128 + kq) ^ ((c & 7) << 3);
    *(short8*)&lds_b1[idx] = w;
  }
  {
    int c = tid >> 3, kq = (tid & 7) * 8;
    if (c < 32) {
      short8 w = *(const short8*)(W2t + c * 64 + kq);
      int idx = (c * 64 + kq) ^ ((c & 7) << 3);
      *(short8*)&lds_b2[idx] = w;
    }
  }
  if (tid < 64) {
    int c = tid >> 2, kq = (tid & 3) * 8;
    short8 w = *(const short8*)(W3t + c * 32 + kq);
    int idx = (c * 32 + kq) ^ ((c & 3) << 3);
    *(short8*)&lds_b3[idx] = w;
  }
  __syncthreads();

  int arow = wid * 16 + (lane & 15);
  int kq8 = (lane >> 4) * 8;
  int cbase = lane & 15;

  // ---- stage 1: 128 -> 64 ----
  f32x4 acc1[4];
#pragma unroll
  for (int f = 0; f < 4; ++f)
#pragma unroll
    for (int j = 0; j < 4; ++j) acc1[f][j] = 0.f;
  {
    short8 a0 = *(short8*)&lds_a[(arow * 128 + kq8) ^ ((arow & 7) << 3)];
    short8 a1 = *(short8*)&lds_a[(arow * 128 + 32 + kq8) ^ ((arow & 7) << 3)];
    short8 a2 = *(short8*)&lds_a[(arow * 128 + 64 + kq8) ^ ((arow & 7) << 3)];
    short8 a3 = *(short8*)&lds_a[(arow * 128 + 96 + kq8) ^ ((arow & 7) << 3)];
#pragma unroll
    for (int f = 0; f < 4; ++f) {
      int c = f * 16 + cbase;
      short8 b0 = *(short8*)&lds_b1[(c * 128 + kq8) ^ ((c & 7) << 3)];
      short8 bb1 = *(short8*)&lds_b1[(c * 128 + 32 + kq8) ^ ((c & 7) << 3)];
      short8 b2v = *(short8*)&lds_b1[(c * 128 + 64 + kq8) ^ ((c & 7) << 3)];
      short8 b3v = *(short8*)&lds_b1[(c * 128 + 96 + kq8) ^ ((c & 7) << 3)];
      acc1[f] = __builtin_amdgcn_mfma_f32_16x16x32_bf16(a0, b0, acc1[f], 0, 0, 0);
      acc1[f] = __builtin_amdgcn_mfma_f32_16x16x32_bf16(a1, bb1, acc1[f], 0, 0, 0);
      acc1[f] = __builtin_amdgcn_mfma_f32_16x16x32_bf16(a2, b2v, acc1[f], 0, 0, 0);
      acc1[f] = __builtin_amdgcn_mfma_f32_16x16x32_bf16(a3, b3v, acc1[f], 0, 0, 0);
    }
  }
  {
    float s[4] = {0, 0, 0, 0}, q[4] = {0, 0, 0, 0};
#pragma unroll
    for (int f = 0; f < 4; ++f) {
      int c = f * 16 + cbase;
      float bias = b1[c];
#pragma unroll
      for (int j = 0; j < 4; ++j) {
        float v = acc1[f][j] + bias;
        acc1[f][j] = v;
        s[j] += v; q[j] += v * v;
      }
    }
#pragma unroll
    for (int off = 8; off >= 1; off >>= 1)
#pragma unroll
      for (int j = 0; j < 4; ++j) {
        s[j] += __shfl_xor(s[j], off);
        q[j] += __shfl_xor(q[j], off);
      }
#pragma unroll
    for (int j = 0; j < 4; ++j) {
      int row = wid * 16 + (lane >> 4) * 4 + j;
      float mu = s[j] * (1.f / 64.f);
      float var = q[j] * (1.f / 64.f) - mu * mu;
      float rs = rsqrtf(var + 1e-5f);
#pragma unroll
      for (int f = 0; f < 4; ++f) {
        int c = f * 16 + cbase;
        float y = fmaxf((acc1[f][j] - mu) * rs * g1[c] + be1[c], 0.f);
        lds_h1[(row * 64 + c) ^ ((row & 7) << 3)] = f2bf(y);
      }
    }
  }
  __syncthreads();

  // ---- stage 2: 64 -> 32 ----
  f32x4 acc2[2];
#pragma unroll
  for (int f = 0; f < 2; ++f)
#pragma unroll
    for (int j = 0; j < 4; ++j) acc2[f][j] = 0.f;
  {
    short8 a0 = *(short8*)&lds_h1[(arow * 64 + kq8) ^ ((arow & 7) << 3)];
    short8 a1 = *(short8*)&lds_h1[(arow * 64 + 32 + kq8) ^ ((arow & 7) << 3)];
#pragma unroll
    for (int f = 0; f < 2; ++f) {
      int c = f * 16 + cbase;
      short8 b0 = *(short8*)&lds_b2[(c * 64 + kq8) ^ ((c & 7) << 3)];
      short8 bb1 = *(short8*)&lds_b2[(c * 64 + 32 + kq8) ^ ((c & 7) << 3)];
      acc2[f] = __builtin_amdgcn_mfma_f32_16x16x32_bf16(a0, b0, acc2[f], 0, 0, 0);
      acc2[f] = __builtin_amdgcn_mfma_f32_16x16x32_bf16(a1, bb1, acc2[f], 0, 0, 0);
    }
  }
  {
    float s[4] = {0, 0, 0, 0}, q[4] = {0, 0, 0, 0};
#pragma unroll
    for (int f = 0; f < 2; ++f) {
      int c = f * 16 + cbase;
      float bias = b2[c];
#pragma unroll
      for (int j = 0; j < 4; ++j) {
        float v = acc2[f][j] + bias;
        acc2[f][j] = v;
        s[j] += v; q[j] += v * v;
      }
    }
#pragma unroll
    for (int off = 8; off >= 1; off >>= 1)
#pragma unroll
      for (int j = 0; j < 4; ++j) {
        s[j] += __shfl_xor(s[j], off);
        q[j] += __shfl_xor(q[j], off);
      }
#pragma unroll
    for (int j = 0; j < 4; ++j) {
      int row = wid * 16 + (lane >> 4) * 4 + j;
      float mu = s[j] * (1.f / 32.f);
      float var = q[j] * (1.f / 32.f) - mu * mu;
      float rs = rsqrtf(var + 1e-5f);
#pragma unroll
      for (int f = 0; f < 2; ++f) {
        int c = f * 16 + cbase;
        float y = fmaxf((acc2[f][j] - mu) * rs * g2[c] + be2[c], 0.f);
        lds_h2[(row * 32 + c) ^ ((row & 3) << 3)] = f2bf(y);
      }
    }
  }
  __syncthreads();

  // ---- stage 3: 32 -> 8 (cols padded to 16) ----
  f32x4 acc3;
#pragma unroll
  for (int j = 0; j < 4; ++j) acc3[j] = 0.f;
  {
    short8 a = *(short8*)&lds_h2[(arow * 32 + kq8) ^ ((arow & 3) << 3)];
    short8 b = *(short8*)&lds_b3[(cbase * 32 + kq8) ^ ((cbase & 3) << 3)];
    acc3 = __builtin_amdgcn_mfma_f32_16x16x32_bf16(a, b, acc3, 0, 0, 0);
  }
  if (cbase < N_CLASSES) {
    float bias = b3[cbase];
#pragma unroll
    for (int j = 0; j < 4; ++j) {
      size_t row = row0 + wid * 16 + (lane >> 4) * 4 + j;
      if (row < N_NODES) out[row * N_CLASSES + cbase] = acc3[j] + bias;
    }
  }
}

// ---------------- launch ----------------
extern "C" void kernel_launch(void* const* d_in, const int* in_sizes, int n_in,
                              void* d_out, int out_size, void* d_ws, size_t ws_size,
                              hipStream_t stream) {
  const float* x     = (const float*)d_in[0];
  const int*   esrc  = (const int*)d_in[1];
  const int*   edst  = (const int*)d_in[2];
  const float* W_in  = (const float*)d_in[3];
  const float* b_in  = (const float*)d_in[4];
  const float* g_in  = (const float*)d_in[5];
  const float* be_in = (const float*)d_in[6];
  const float* Wc    = (const float*)d_in[7];
  const float* a_src = (const float*)d_in[8];
  const float* a_dst = (const float*)d_in[9];
  const float* bc    = (const float*)d_in[10];
  const float* gc    = (const float*)d_in[11];
  const float* bec   = (const float*)d_in[12];
  const float* W1    = (const float*)d_in[13];
  const float* b1    = (const float*)d_in[14];
  const float* g1    = (const float*)d_in[15];
  const float* be1   = (const float*)d_in[16];
  const float* W2    = (const float*)d_in[17];
  const float* b2    = (const float*)d_in[18];
  const float* g2    = (const float*)d_in[19];
  const float* be2   = (const float*)d_in[20];
  const float* W3    = (const float*)d_in[21];
  const float* b3    = (const float*)d_in[22];

  float* ws = (float*)d_ws;
  const size_t NH = (size_t)N_NODES * HID;
  float* hA = ws;
  float* hB = hA + NH;
  float* es = hB + NH;
  float* ed = es + (size_t)N_NODES * HEADS;
  unsigned short* hp_bf = (unsigned short*)(ed + (size_t)N_NODES * HEADS);
  int* deg2  = (int*)(hp_bf + NH);                 // [4N]
  int* cur2  = deg2 + NRANGE * N_NODES;            // [4N]
  int* offs2 = cur2 + NRANGE * N_NODES;            // [4N+1]
  int* col   = offs2 + NRANGE * N_NODES + 1;
  uintptr_t wp = (uintptr_t)(col + N_EDGES);
  wp = (wp + 15) & ~(uintptr_t)15;
  unsigned short* Wt_in = (unsigned short*)wp;
  unsigned short* Wt_c  = Wt_in + (size_t)IN_DIM * HID;
  unsigned short* W1t   = Wt_c + (size_t)N_LAYERS * HID * HID;
  unsigned short* W2t   = W1t + 64 * 128;
  unsigned short* W3t   = W2t + 32 * 64;

  // weights -> bf16 transposed + zero deg2/cur2 (merged)
  k_prep<<<(2 * NRANGE * N_NODES + 255) / 256, 256, 0, stream>>>(
      W_in, Wc, W1, W2, W3, Wt_in, Wt_c, W1t, W2t, W3t, deg2);

  // input projection + LN + relu (MFMA)
  k_gemm_in<<<(N_NODES + 63) / 64, 256, 0, stream>>>(x, Wt_in, b_in, g_in, be_in, hA);

  // CSR build, src-range bucketed (reused across all 3 layers)
  k_count<<<(N_EDGES + 255) / 256, 256, 0, stream>>>(esrc, edst, deg2);
  k_scan<<<1, 1024, 0, stream>>>(deg2, offs2);
  k_scatter<<<(N_EDGES + 255) / 256, 256, 0, stream>>>(esrc, edst, offs2, cur2, col);

  float* hcur = hA;
  float* hnext = hB;
  for (int l = 0; l < N_LAYERS; ++l) {
    k_gemm_gat<<<(N_NODES + 63) / 64, 256, 0, stream>>>(
        hcur, Wt_c + (size_t)l * HID * HID,
        a_src + (size_t)l * HEADS * HEAD_DIM, a_dst + (size_t)l * HEADS * HEAD_DIM,
        hp_bf, es, ed);
    k_gat_agg<<<(N_NODES + 3) / 4, 256, 0, stream>>>(
        hp_bf, es, ed, offs2, col,
        bc + (size_t)l * HID, gc + (size_t)l * HID, bec + (size_t)l * HID,
        hcur, hnext, l > 0 ? 1 : 0);
    float* t = hcur; hcur = hnext; hnext = t;
  }

  k_head_mfma<<<(N_NODES + 63) / 64, 256, 0, stream>>>(
      hcur, W1t, b1, g1, be1, W2t, b2, g2, be2, W3t, b3, (float*)d_out);
}

// Round 12
// 345.548 us; speedup vs baseline: 1.5006x; 1.4958x over previous
//
#include <hip/hip_runtime.h>
#include <math.h>

#define N_NODES 50000
#define N_EDGES 800000
#define IN_DIM 512
#define HID 128
#define HEADS 8
#define HEAD_DIM 16
#define N_LAYERS 3
#define N_CLASSES 8
#define LOG2E 1.4426950408889634f

typedef __attribute__((ext_vector_type(8))) short short8;
typedef __attribute__((ext_vector_type(4))) short short4v;
typedef __attribute__((ext_vector_type(4))) float f32x4;

__device__ inline unsigned short f2bf(float f) {
  unsigned u = __float_as_uint(f);
  u = (u + 0x7fffu + ((u >> 16) & 1u)) >> 16;
  return (unsigned short)u;
}
__device__ inline float bflo(unsigned u) { return __uint_as_float(u << 16); }
__device__ inline float bfhi(unsigned u) { return __uint_as_float(u & 0xffff0000u); }

// ---------------- prep: weight fp32->bf16 transpose + zero deg/cur/total ----------------
__global__ __launch_bounds__(256) void k_prep(
    const float* __restrict__ W_in, const float* __restrict__ Wc,
    const float* __restrict__ W1, const float* __restrict__ W2,
    const float* __restrict__ W3,
    unsigned short* __restrict__ Wt_in, unsigned short* __restrict__ Wt_c,
    unsigned short* __restrict__ W1t, unsigned short* __restrict__ W2t,
    unsigned short* __restrict__ W3t, int* __restrict__ degcur,
    int* __restrict__ total) {
  int i = blockIdx.x * blockDim.x + threadIdx.x;
  if (i == 0) total[0] = 0;
  if (i < 2 * N_NODES) degcur[i] = 0;
  if (i < IN_DIM * HID) {                      // Wt_in[c][k]
    int c = i >> 9, k = i & 511;
    Wt_in[i] = f2bf(W_in[k * HID + c]);
  }
  if (i < N_LAYERS * HID * HID) {              // Wt_c[l][c][k]
    int l = i >> 14, r = i & 16383, c = r >> 7, k = r & 127;
    Wt_c[i] = f2bf(Wc[l * HID * HID + k * HID + c]);
  }
  if (i < 64 * 128) {                          // W1t[c][k]
    int c = i >> 7, k = i & 127;
    W1t[i] = f2bf(W1[k * 64 + c]);
  }
  if (i < 32 * 64) {                           // W2t[c][k]
    int c = i >> 6, k = i & 63;
    W2t[i] = f2bf(W2[k * 32 + c]);
  }
  if (i < 16 * 32) {                           // W3t[c][k], cols 8..15 zero-padded
    int c = i >> 5, k = i & 31;
    W3t[i] = (c < 8) ? f2bf(W3[k * N_CLASSES + c]) : 0;
  }
}

// ---------------- MFMA GEMM mainloop: C[64 x 128] += A_f32[64 x K] @ W_bf16t ----------------
template <int K>
__device__ inline void gemm_mainloop(const float* __restrict__ A, size_t row0,
                                     const unsigned short* __restrict__ Wt,
                                     unsigned short* lds_a, unsigned short* lds_b,
                                     f32x4 acc[8]) {
  const int tid = threadIdx.x;
  const int lane = tid & 63, wid = tid >> 6;
#pragma unroll
  for (int f = 0; f < 8; ++f)
#pragma unroll
    for (int j = 0; j < 4; ++j) acc[f][j] = 0.f;

  for (int kb = 0; kb < K; kb += 64) {
#pragma unroll
    for (int j = 0; j < 4; ++j) {
      int i = tid + j * 256;
      int r = i >> 4, kq = (i & 15) * 4;
      size_t rg = row0 + r;
      if (rg >= N_NODES) rg = N_NODES - 1;
      float4 v = *(const float4*)(A + rg * K + kb + kq);
      short4v b4;
      b4[0] = (short)f2bf(v.x); b4[1] = (short)f2bf(v.y);
      b4[2] = (short)f2bf(v.z); b4[3] = (short)f2bf(v.w);
      int idx = (r * 64 + kq) ^ ((r & 7) << 3);
      *(short4v*)&lds_a[idx] = b4;
    }
#pragma unroll
    for (int j = 0; j < 4; ++j) {
      int i = tid + j * 256;
      int c = i >> 3, kq = (i & 7) * 8;
      short8 w = *(const short8*)(Wt + (size_t)c * K + kb + kq);
      int idx = (c * 64 + kq) ^ ((c & 7) << 3);
      *(short8*)&lds_b[idx] = w;
    }
    __syncthreads();

    int arow = wid * 16 + (lane & 15);
    int kq8 = (lane >> 4) * 8;
    short8 a0 = *(short8*)&lds_a[(arow * 64 + kq8) ^ ((arow & 7) << 3)];
    short8 a1 = *(short8*)&lds_a[(arow * 64 + 32 + kq8) ^ ((arow & 7) << 3)];
#pragma unroll
    for (int f = 0; f < 8; ++f) {
      int c = f * 16 + (lane & 15);
      short8 b0 = *(short8*)&lds_b[(c * 64 + kq8) ^ ((c & 7) << 3)];
      short8 b1 = *(short8*)&lds_b[(c * 64 + 32 + kq8) ^ ((c & 7) << 3)];
      acc[f] = __builtin_amdgcn_mfma_f32_16x16x32_bf16(a0, b0, acc[f], 0, 0, 0);
      acc[f] = __builtin_amdgcn_mfma_f32_16x16x32_bf16(a1, b1, acc[f], 0, 0, 0);
    }
    __syncthreads();
  }
}

// ---------------- input projection GEMM + bias + LN + relu ----------------
__global__ __launch_bounds__(256) void k_gemm_in(
    const float* __restrict__ x, const unsigned short* __restrict__ Wt,
    const float* __restrict__ b, const float* __restrict__ g,
    const float* __restrict__ be, float* __restrict__ h0) {
  __shared__ unsigned short lds_a[64 * 64];
  __shared__ unsigned short lds_b[128 * 64];
  f32x4 acc[8];
  size_t row0 = (size_t)blockIdx.x * 64;
  gemm_mainloop<IN_DIM>(x, row0, Wt, lds_a, lds_b, acc);

  int lane = threadIdx.x & 63, wid = threadIdx.x >> 6;
  int cbase = lane & 15;
  float s[4] = {0.f, 0.f, 0.f, 0.f}, q[4] = {0.f, 0.f, 0.f, 0.f};
  float gg[8], bb[8];
#pragma unroll
  for (int f = 0; f < 8; ++f) {
    int c = f * 16 + cbase;
    float bias = b[c];
    gg[f] = g[c]; bb[f] = be[c];
#pragma unroll
    for (int j = 0; j < 4; ++j) {
      float v = acc[f][j] + bias;
      acc[f][j] = v;
      s[j] += v; q[j] += v * v;
    }
  }
#pragma unroll
  for (int off = 8; off >= 1; off >>= 1)
#pragma unroll
    for (int j = 0; j < 4; ++j) {
      s[j] += __shfl_xor(s[j], off);
      q[j] += __shfl_xor(q[j], off);
    }
#pragma unroll
  for (int j = 0; j < 4; ++j) {
    size_t row = row0 + wid * 16 + (lane >> 4) * 4 + j;
    if (row < N_NODES) {
      float mu = s[j] * (1.f / 128.f);
      float var = q[j] * (1.f / 128.f) - mu * mu;
      float rs = rsqrtf(var + 1e-5f);
#pragma unroll
      for (int f = 0; f < 8; ++f) {
        float y = (acc[f][j] - mu) * rs * gg[f] + bb[f];
        h0[row * HID + f * 16 + cbase] = fmaxf(y, 0.f);
      }
    }
  }
}

// ---------------- GAT projection GEMM + hp(bf16) store + es/ed (pre-scaled by log2e) ----------------
__global__ __launch_bounds__(256) void k_gemm_gat(
    const float* __restrict__ h, const unsigned short* __restrict__ Wt,
    const float* __restrict__ asrc, const float* __restrict__ adst,
    unsigned short* __restrict__ hp_bf, float* __restrict__ es,
    float* __restrict__ ed) {
  __shared__ unsigned short lds_a[64 * 64];
  __shared__ unsigned short lds_b[128 * 64];
  f32x4 acc[8];
  size_t row0 = (size_t)blockIdx.x * 64;
  gemm_mainloop<HID>(h, row0, Wt, lds_a, lds_b, acc);

  int lane = threadIdx.x & 63, wid = threadIdx.x >> 6;
  int cbase = lane & 15;
#pragma unroll
  for (int f = 0; f < 8; ++f) {   // frag f == head f (cols f*16..f*16+15)
    float av = asrc[f * 16 + cbase], bv = adst[f * 16 + cbase];
    float eS[4], eD[4];
#pragma unroll
    for (int j = 0; j < 4; ++j) { eS[j] = acc[f][j] * av; eD[j] = acc[f][j] * bv; }
#pragma unroll
    for (int off = 8; off >= 1; off >>= 1)
#pragma unroll
      for (int j = 0; j < 4; ++j) {
        eS[j] += __shfl_xor(eS[j], off);
        eD[j] += __shfl_xor(eD[j], off);
      }
#pragma unroll
    for (int j = 0; j < 4; ++j) {
      size_t row = row0 + wid * 16 + (lane >> 4) * 4 + j;
      if (row < N_NODES) {
        hp_bf[row * HID + f * 16 + cbase] = f2bf(acc[f][j]);
        if (cbase == 0) {
          es[row * HEADS + f] = eS[j] * LOG2E;
          ed[row * HEADS + f] = eD[j] * LOG2E;
        }
      }
    }
  }
}

// ---------------- CSR build: count -> atomic segment assign (no scan) -> scatter ------
__global__ void k_count(const int* __restrict__ dst, int* __restrict__ deg) {
  int e = blockIdx.x * blockDim.x + threadIdx.x;
  if (e < N_EDGES) atomicAdd(&deg[dst[e]], 1);
}

// start[n] = atomicAdd(total, deg[n]) — wave-aggregated by the AMDGPU atomic optimizer.
// Node segments are disjoint/contiguous; global order is arbitrary (irrelevant).
__global__ void k_assign(const int* __restrict__ deg, int* __restrict__ start,
                         int* __restrict__ total) {
  int n = blockIdx.x * blockDim.x + threadIdx.x;
  if (n < N_NODES) start[n] = atomicAdd(total, deg[n]);
}

__global__ void k_scatter(const int* __restrict__ src, const int* __restrict__ dst,
                          const int* __restrict__ start, int* __restrict__ cur,
                          int* __restrict__ col) {
  int e = blockIdx.x * blockDim.x + threadIdx.x;
  if (e < N_EDGES) {
    int d = dst[e];
    int pos = start[d] + atomicAdd(&cur[d], 1);
    col[pos] = src[e];
  }
}

// ---------------- GAT aggregation: wave/node, 8-edge batched, 2-deep software pipeline ----
__global__ __launch_bounds__(256) void k_gat_agg(
    const unsigned short* __restrict__ hp_bf, const float* __restrict__ es,
    const float* __restrict__ ed, const int* __restrict__ start,
    const int* __restrict__ deg, const int* __restrict__ col,
    const float* __restrict__ bc, const float* __restrict__ gc,
    const float* __restrict__ bec, const float* __restrict__ h_res,
    float* __restrict__ h_out, int use_res) {
  int lane = threadIdx.x & 63;
  int n = blockIdx.x * 4 + (threadIdx.x >> 6);
  if (n >= N_NODES) return;
  int head = lane >> 3;
  int sub = lane & 7;
  int hbase = head * 8;
  const unsigned* hpu = (const unsigned*)hp_bf;  // 2 bf16 channels per uint

  float edv = ed[(size_t)n * HEADS + head];
  float z0 = es[(size_t)n * HEADS + head] + edv;
  z0 = fmaxf(z0, 0.2f * z0);            // leaky_relu (pre-scaled by log2e)
  float p0 = exp2f(z0);                 // self-loop weight
  unsigned su = hpu[(size_t)n * 64 + lane];

  float den0 = p0, ax0 = p0 * bflo(su), ay0 = p0 * bfhi(su);
  float den1 = 0.f, ax1 = 0.f, ay1 = 0.f;

  int s0 = start[n], s1 = s0 + deg[n];
  int nb = (s1 - s0) >> 3;
  int base = s0;
  int se = 0;
  float p = 0.f;
  if (nb > 0) {                          // prologue: batch 0 logits
    se = col[base + sub];
    float z = es[(size_t)se * HEADS + head] + edv;
    z = fmaxf(z, 0.2f * z);
    p = exp2f(z);
  }
  for (int t = 0; t < nb; ++t) {
    int seN = 0;
    bool more = (t + 1 < nb);
    if (more) seN = col[base + 8 + sub]; // issue next col load first
#pragma unroll
    for (int k = 0; k < 8; k += 2) {     // current batch hp gathers + accumulate
      float pk0 = __shfl(p, hbase + k);
      float pk1 = __shfl(p, hbase + k + 1);
      int sk0 = __shfl(se, k);
      int sk1 = __shfl(se, k + 1);
      unsigned h0 = hpu[(size_t)sk0 * 64 + lane];
      unsigned h1 = hpu[(size_t)sk1 * 64 + lane];
      den0 += pk0;
      ax0 = fmaf(pk0, bflo(h0), ax0);
      ay0 = fmaf(pk0, bfhi(h0), ay0);
      den1 += pk1;
      ax1 = fmaf(pk1, bflo(h1), ax1);
      ay1 = fmaf(pk1, bfhi(h1), ay1);
    }
    if (more) {                          // next batch logits (overlapped with hp waits)
      float zN = es[(size_t)seN * HEADS + head] + edv;
      zN = fmaxf(zN, 0.2f * zN);
      p = exp2f(zN);
      se = seN;
    }
    base += 8;
  }
  int rem = s1 - base;
  if (rem > 0) {
    int e = base + (sub < rem ? sub : rem - 1);
    int set = col[e];
    float z = es[(size_t)set * HEADS + head] + edv;
    z = fmaxf(z, 0.2f * z);
    float pt = (sub < rem) ? exp2f(z) : 0.f;
    for (int k = 0; k < rem; ++k) {
      float pk = __shfl(pt, hbase + k);
      int sk = __shfl(set, k);
      unsigned hk = hpu[(size_t)sk * 64 + lane];
      den0 += pk;
      ax0 = fmaf(pk, bflo(hk), ax0);
      ay0 = fmaf(pk, bfhi(hk), ay0);
    }
  }
  float den = den0 + den1 + 1e-16f;
  float rden = 1.f / den;
  float v0 = (ax0 + ax1) * rden + bc[2 * lane];
  float v1 = (ay0 + ay1) * rden + bc[2 * lane + 1];

  float s = v0 + v1, q = v0 * v0 + v1 * v1;
#pragma unroll
  for (int off = 32; off >= 1; off >>= 1) {
    s += __shfl_xor(s, off);
    q += __shfl_xor(q, off);
  }
  float mu = s * (1.f / 128.f);
  float var = q * (1.f / 128.f) - mu * mu;
  float rs = rsqrtf(var + 1e-5f);
  float y0 = fmaxf((v0 - mu) * rs * gc[2 * lane] + bec[2 * lane], 0.f);
  float y1 = fmaxf((v1 - mu) * rs * gc[2 * lane + 1] + bec[2 * lane + 1], 0.f);
  if (use_res) {
    float2 r = ((const float2*)h_res)[(size_t)n * 64 + lane];
    y0 += r.x; y1 += r.y;
  }
  ((float2*)h_out)[(size_t)n * 64 + lane] = make_float2(y0, y1);
}

// ---------------- classifier head: fused 3-stage MFMA MLP ----------------
__global__ __launch_bounds__(256) void k_head_mfma(
    const float* __restrict__ h,
    const unsigned short* __restrict__ W1t, const float* __restrict__ b1,
    const float* __restrict__ g1, const float* __restrict__ be1,
    const unsigned short* __restrict__ W2t, const float* __restrict__ b2,
    const float* __restrict__ g2, const float* __restrict__ be2,
    const unsigned short* __restrict__ W3t, const float* __restrict__ b3,
    float* __restrict__ out) {
  __shared__ unsigned short lds_a[64 * 128];
  __shared__ unsigned short lds_b1[64 * 128];
  __shared__ unsigned short lds_h1[64 * 64];
  __shared__ unsigned short lds_b2[32 * 64];
  __shared__ unsigned short lds_h2[64 * 32];
  __shared__ unsigned short lds_b3[16 * 32];
  int tid = threadIdx.x, lane = tid & 63, wid = tid >> 6;
  size_t row0 = (size_t)blockIdx.x * 64;

#pragma unroll
  for (int jj = 0; jj < 8; ++jj) {
    int i = tid + jj * 256;
    int r = i >> 5, kq = (i & 31) * 4;
    size_t rg = row0 + r;
    if (rg >= N_NODES) rg = N_NODES - 1;
    float4 v = *(const float4*)(h + rg * HID + kq);
    short4v b4;
    b4[0] = (short)f2bf(v.x); b4[1] = (short)f2bf(v.y);
    b4[2] = (short)f2bf(v.z); b4[3] = (short)f2bf(v.w);
    int idx = (r * 128 + kq) ^ ((r & 7) << 3);
    *(short4v*)&lds_a[idx] = b4;
  }
#pragma unroll
  for (int jj = 0; jj < 4; ++jj) {
    int i = tid + jj * 256;
    int c = i >> 4, kq = (i & 15) * 8;
    short8 w = *(const short8*)(W1t + c * 128 + kq);
    int idx = (c * 128 + kq) ^ ((c & 7) << 3);
    *(short8*)&lds_b1[idx] = w;
  }
  {
    int c = tid >> 3, kq = (tid & 7) * 8;
    if (c < 32) {
      short8 w = *(const short8*)(W2t + c * 64 + kq);
      int idx = (c * 64 + kq) ^ ((c & 7) << 3);
      *(short8*)&lds_b2[idx] = w;
    }
  }
  if (tid < 64) {
    int c = tid >> 2, kq = (tid & 3) * 8;
    short8 w = *(const short8*)(W3t + c * 32 + kq);
    int idx = (c * 32 + kq) ^ ((c & 3) << 3);
    *(short8*)&lds_b3[idx] = w;
  }
  __syncthreads();

  int arow = wid * 16 + (lane & 15);
  int kq8 = (lane >> 4) * 8;
  int cbase = lane & 15;

  // ---- stage 1: 128 -> 64 ----
  f32x4 acc1[4];
#pragma unroll
  for (int f = 0; f < 4; ++f)
#pragma unroll
    for (int j = 0; j < 4; ++j) acc1[f][j] = 0.f;
  {
    short8 a0 = *(short8*)&lds_a[(arow * 128 + kq8) ^ ((arow & 7) << 3)];
    short8 a1 = *(short8*)&lds_a[(arow * 128 + 32 + kq8) ^ ((arow & 7) << 3)];
    short8 a2 = *(short8*)&lds_a[(arow * 128 + 64 + kq8) ^ ((arow & 7) << 3)];
    short8 a3 = *(short8*)&lds_a[(arow * 128 + 96 + kq8) ^ ((arow & 7) << 3)];
#pragma unroll
    for (int f = 0; f < 4; ++f) {
      int c = f * 16 + cbase;
      short8 b0 = *(short8*)&lds_b1[(c * 128 + kq8) ^ ((c & 7) << 3)];
      short8 bb1 = *(short8*)&lds_b1[(c * 128 + 32 + kq8) ^ ((c & 7) << 3)];
      short8 b2v = *(short8*)&lds_b1[(c * 128 + 64 + kq8) ^ ((c & 7) << 3)];
      short8 b3v = *(short8*)&lds_b1[(c * 128 + 96 + kq8) ^ ((c & 7) << 3)];
      acc1[f] = __builtin_amdgcn_mfma_f32_16x16x32_bf16(a0, b0, acc1[f], 0, 0, 0);
      acc1[f] = __builtin_amdgcn_mfma_f32_16x16x32_bf16(a1, bb1, acc1[f], 0, 0, 0);
      acc1[f] = __builtin_amdgcn_mfma_f32_16x16x32_bf16(a2, b2v, acc1[f], 0, 0, 0);
      acc1[f] = __builtin_amdgcn_mfma_f32_16x16x32_bf16(a3, b3v, acc1[f], 0, 0, 0);
    }
  }
  {
    float s[4] = {0, 0, 0, 0}, q[4] = {0, 0, 0, 0};
#pragma unroll
    for (int f = 0; f < 4; ++f) {
      int c = f * 16 + cbase;
      float bias = b1[c];
#pragma unroll
      for (int j = 0; j < 4; ++j) {
        float v = acc1[f][j] + bias;
        acc1[f][j] = v;
        s[j] += v; q[j] += v * v;
      }
    }
#pragma unroll
    for (int off = 8; off >= 1; off >>= 1)
#pragma unroll
      for (int j = 0; j < 4; ++j) {
        s[j] += __shfl_xor(s[j], off);
        q[j] += __shfl_xor(q[j], off);
      }
#pragma unroll
    for (int j = 0; j < 4; ++j) {
      int row = wid * 16 + (lane >> 4) * 4 + j;
      float mu = s[j] * (1.f / 64.f);
      float var = q[j] * (1.f / 64.f) - mu * mu;
      float rs = rsqrtf(var + 1e-5f);
#pragma unroll
      for (int f = 0; f < 4; ++f) {
        int c = f * 16 + cbase;
        float y = fmaxf((acc1[f][j] - mu) * rs * g1[c] + be1[c], 0.f);
        lds_h1[(row * 64 + c) ^ ((row & 7) << 3)] = f2bf(y);
      }
    }
  }
  __syncthreads();

  // ---- stage 2: 64 -> 32 ----
  f32x4 acc2[2];
#pragma unroll
  for (int f = 0; f < 2; ++f)
#pragma unroll
    for (int j = 0; j < 4; ++j) acc2[f][j] = 0.f;
  {
    short8 a0 = *(short8*)&lds_h1[(arow * 64 + kq8) ^ ((arow & 7) << 3)];
    short8 a1 = *(short8*)&lds_h1[(arow * 64 + 32 + kq8) ^ ((arow & 7) << 3)];
#pragma unroll
    for (int f = 0; f < 2; ++f) {
      int c = f * 16 + cbase;
      short8 b0 = *(short8*)&lds_b2[(c * 64 + kq8) ^ ((c & 7) << 3)];
      short8 bb1 = *(short8*)&lds_b2[(c * 64 + 32 + kq8) ^ ((c & 7) << 3)];
      acc2[f] = __builtin_amdgcn_mfma_f32_16x16x32_bf16(a0, b0, acc2[f], 0, 0, 0);
      acc2[f] = __builtin_amdgcn_mfma_f32_16x16x32_bf16(a1, bb1, acc2[f], 0, 0, 0);
    }
  }
  {
    float s[4] = {0, 0, 0, 0}, q[4] = {0, 0, 0, 0};
#pragma unroll
    for (int f = 0; f < 2; ++f) {
      int c = f * 16 + cbase;
      float bias = b2[c];
#pragma unroll
      for (int j = 0; j < 4; ++j) {
        float v = acc2[f][j] + bias;
        acc2[f][j] = v;
        s[j] += v; q[j] += v * v;
      }
    }
#pragma unroll
    for (int off = 8; off >= 1; off >>= 1)
#pragma unroll
      for (int j = 0; j < 4; ++j) {
        s[j] += __shfl_xor(s[j], off);
        q[j] += __shfl_xor(q[j], off);
      }
#pragma unroll
    for (int j = 0; j < 4; ++j) {
      int row = wid * 16 + (lane >> 4) * 4 + j;
      float mu = s[j] * (1.f / 32.f);
      float var = q[j] * (1.f / 32.f) - mu * mu;
      float rs = rsqrtf(var + 1e-5f);
#pragma unroll
      for (int f = 0; f < 2; ++f) {
        int c = f * 16 + cbase;
        float y = fmaxf((acc2[f][j] - mu) * rs * g2[c] + be2[c], 0.f);
        lds_h2[(row * 32 + c) ^ ((row & 3) << 3)] = f2bf(y);
      }
    }
  }
  __syncthreads();

  // ---- stage 3: 32 -> 8 (cols padded to 16) ----
  f32x4 acc3;
#pragma unroll
  for (int j = 0; j < 4; ++j) acc3[j] = 0.f;
  {
    short8 a = *(short8*)&lds_h2[(arow * 32 + kq8) ^ ((arow & 3) << 3)];
    short8 b = *(short8*)&lds_b3[(cbase * 32 + kq8) ^ ((cbase & 3) << 3)];
    acc3 = __builtin_amdgcn_mfma_f32_16x16x32_bf16(a, b, acc3, 0, 0, 0);
  }
  if (cbase < N_CLASSES) {
    float bias = b3[cbase];
#pragma unroll
    for (int j = 0; j < 4; ++j) {
      size_t row = row0 + wid * 16 + (lane >> 4) * 4 + j;
      if (row < N_NODES) out[row * N_CLASSES + cbase] = acc3[j] + bias;
    }
  }
}

// ---------------- launch ----------------
extern "C" void kernel_launch(void* const* d_in, const int* in_sizes, int n_in,
                              void* d_out, int out_size, void* d_ws, size_t ws_size,
                              hipStream_t stream) {
  const float* x     = (const float*)d_in[0];
  const int*   esrc  = (const int*)d_in[1];
  const int*   edst  = (const int*)d_in[2];
  const float* W_in  = (const float*)d_in[3];
  const float* b_in  = (const float*)d_in[4];
  const float* g_in  = (const float*)d_in[5];
  const float* be_in = (const float*)d_in[6];
  const float* Wc    = (const float*)d_in[7];
  const float* a_src = (const float*)d_in[8];
  const float* a_dst = (const float*)d_in[9];
  const float* bc    = (const float*)d_in[10];
  const float* gc    = (const float*)d_in[11];
  const float* bec   = (const float*)d_in[12];
  const float* W1    = (const float*)d_in[13];
  const float* b1    = (const float*)d_in[14];
  const float* g1    = (const float*)d_in[15];
  const float* be1   = (const float*)d_in[16];
  const float* W2    = (const float*)d_in[17];
  const float* b2    = (const float*)d_in[18];
  const float* g2    = (const float*)d_in[19];
  const float* be2   = (const float*)d_in[20];
  const float* W3    = (const float*)d_in[21];
  const float* b3    = (const float*)d_in[22];

  float* ws = (float*)d_ws;
  const size_t NH = (size_t)N_NODES * HID;
  float* hA = ws;
  float* hB = hA + NH;
  float* es = hB + NH;
  float* ed = es + (size_t)N_NODES * HEADS;
  unsigned short* hp_bf = (unsigned short*)(ed + (size_t)N_NODES * HEADS);
  int* deg   = (int*)(hp_bf + NH);
  int* cur   = deg + N_NODES;
  int* startv = cur + N_NODES;
  int* total = startv + N_NODES;
  int* col   = total + 1;
  uintptr_t wp = (uintptr_t)(col + N_EDGES);
  wp = (wp + 15) & ~(uintptr_t)15;
  unsigned short* Wt_in = (unsigned short*)wp;
  unsigned short* Wt_c  = Wt_in + (size_t)IN_DIM * HID;
  unsigned short* W1t   = Wt_c + (size_t)N_LAYERS * HID * HID;
  unsigned short* W2t   = W1t + 64 * 128;
  unsigned short* W3t   = W2t + 32 * 64;

  // weights -> bf16 transposed + zero deg/cur/total (merged)
  k_prep<<<(2 * N_NODES + 255) / 256, 256, 0, stream>>>(
      W_in, Wc, W1, W2, W3, Wt_in, Wt_c, W1t, W2t, W3t, deg, total);

  // input projection + LN + relu (MFMA)
  k_gemm_in<<<(N_NODES + 63) / 64, 256, 0, stream>>>(x, Wt_in, b_in, g_in, be_in, hA);

  // CSR build: count -> atomic segment assign (no scan) -> scatter
  k_count<<<(N_EDGES + 255) / 256, 256, 0, stream>>>(edst, deg);
  k_assign<<<(N_NODES + 255) / 256, 256, 0, stream>>>(deg, startv, total);
  k_scatter<<<(N_EDGES + 255) / 256, 256, 0, stream>>>(esrc, edst, startv, cur, col);

  float* hcur = hA;
  float* hnext = hB;
  for (int l = 0; l < N_LAYERS; ++l) {
    k_gemm_gat<<<(N_NODES + 63) / 64, 256, 0, stream>>>(
        hcur, Wt_c + (size_t)l * HID * HID,
        a_src + (size_t)l * HEADS * HEAD_DIM, a_dst + (size_t)l * HEADS * HEAD_DIM,
        hp_bf, es, ed);
    k_gat_agg<<<(N_NODES + 3) / 4, 256, 0, stream>>>(
        hp_bf, es, ed, startv, deg, col,
        bc + (size_t)l * HID, gc + (size_t)l * HID, bec + (size_t)l * HID,
        hcur, hnext, l > 0 ? 1 : 0);
    float* t = hcur; hcur = hnext; hnext = t;
  }

  k_head_mfma<<<(N_NODES + 63) / 64, 256, 0, stream>>>(
      hcur, W1t, b1, g1, be1, W2t, b2, g2, be2, W3t, b3, (float*)d_out);
}

// Round 13
// 338.325 us; speedup vs baseline: 1.5326x; 1.0213x over previous
//
#include <hip/hip_runtime.h>
#include <math.h>

#define N_NODES 50000
#define N_EDGES 800000
#define IN_DIM 512
#define HID 128
#define HEADS 8
#define HEAD_DIM 16
#define N_LAYERS 3
#define N_CLASSES 8
#define LOG2E 1.4426950408889634f
#define NBLK 196  // ceil(N_NODES/256)

typedef __attribute__((ext_vector_type(8))) short short8;
typedef __attribute__((ext_vector_type(4))) short short4v;
typedef __attribute__((ext_vector_type(4))) float f32x4;

__device__ inline unsigned short f2bf(float f) {
  unsigned u = __float_as_uint(f);
  u = (u + 0x7fffu + ((u >> 16) & 1u)) >> 16;
  return (unsigned short)u;
}
__device__ inline float bflo(unsigned u) { return __uint_as_float(u << 16); }
__device__ inline float bfhi(unsigned u) { return __uint_as_float(u & 0xffff0000u); }

// ---------------- prep: weight fp32->bf16 transpose + zero deg/cur ----------------
__global__ __launch_bounds__(256) void k_prep(
    const float* __restrict__ W_in, const float* __restrict__ Wc,
    const float* __restrict__ W1, const float* __restrict__ W2,
    const float* __restrict__ W3,
    unsigned short* __restrict__ Wt_in, unsigned short* __restrict__ Wt_c,
    unsigned short* __restrict__ W1t, unsigned short* __restrict__ W2t,
    unsigned short* __restrict__ W3t, int* __restrict__ degcur) {
  int i = blockIdx.x * blockDim.x + threadIdx.x;
  if (i < 2 * N_NODES) degcur[i] = 0;
  if (i < IN_DIM * HID) {                      // Wt_in[c][k]
    int c = i >> 9, k = i & 511;
    Wt_in[i] = f2bf(W_in[k * HID + c]);
  }
  if (i < N_LAYERS * HID * HID) {              // Wt_c[l][c][k]
    int l = i >> 14, r = i & 16383, c = r >> 7, k = r & 127;
    Wt_c[i] = f2bf(Wc[l * HID * HID + k * HID + c]);
  }
  if (i < 64 * 128) {                          // W1t[c][k]
    int c = i >> 7, k = i & 127;
    W1t[i] = f2bf(W1[k * 64 + c]);
  }
  if (i < 32 * 64) {                           // W2t[c][k]
    int c = i >> 6, k = i & 63;
    W2t[i] = f2bf(W2[k * 32 + c]);
  }
  if (i < 16 * 32) {                           // W3t[c][k], cols 8..15 zero-padded
    int c = i >> 5, k = i & 31;
    W3t[i] = (c < 8) ? f2bf(W3[k * N_CLASSES + c]) : 0;
  }
}

// ---------------- MFMA GEMM mainloop: C[64 x 128] += A_f32[64 x K] @ W_bf16t ----------------
template <int K>
__device__ inline void gemm_mainloop(const float* __restrict__ A, size_t row0,
                                     const unsigned short* __restrict__ Wt,
                                     unsigned short* lds_a, unsigned short* lds_b,
                                     f32x4 acc[8]) {
  const int tid = threadIdx.x;
  const int lane = tid & 63, wid = tid >> 6;
#pragma unroll
  for (int f = 0; f < 8; ++f)
#pragma unroll
    for (int j = 0; j < 4; ++j) acc[f][j] = 0.f;

  for (int kb = 0; kb < K; kb += 64) {
#pragma unroll
    for (int j = 0; j < 4; ++j) {
      int i = tid + j * 256;
      int r = i >> 4, kq = (i & 15) * 4;
      size_t rg = row0 + r;
      if (rg >= N_NODES) rg = N_NODES - 1;
      float4 v = *(const float4*)(A + rg * K + kb + kq);
      short4v b4;
      b4[0] = (short)f2bf(v.x); b4[1] = (short)f2bf(v.y);
      b4[2] = (short)f2bf(v.z); b4[3] = (short)f2bf(v.w);
      int idx = (r * 64 + kq) ^ ((r & 7) << 3);
      *(short4v*)&lds_a[idx] = b4;
    }
#pragma unroll
    for (int j = 0; j < 4; ++j) {
      int i = tid + j * 256;
      int c = i >> 3, kq = (i & 7) * 8;
      short8 w = *(const short8*)(Wt + (size_t)c * K + kb + kq);
      int idx = (c * 64 + kq) ^ ((c & 7) << 3);
      *(short8*)&lds_b[idx] = w;
    }
    __syncthreads();

    int arow = wid * 16 + (lane & 15);
    int kq8 = (lane >> 4) * 8;
    short8 a0 = *(short8*)&lds_a[(arow * 64 + kq8) ^ ((arow & 7) << 3)];
    short8 a1 = *(short8*)&lds_a[(arow * 64 + 32 + kq8) ^ ((arow & 7) << 3)];
#pragma unroll
    for (int f = 0; f < 8; ++f) {
      int c = f * 16 + (lane & 15);
      short8 b0 = *(short8*)&lds_b[(c * 64 + kq8) ^ ((c & 7) << 3)];
      short8 b1 = *(short8*)&lds_b[(c * 64 + 32 + kq8) ^ ((c & 7) << 3)];
      acc[f] = __builtin_amdgcn_mfma_f32_16x16x32_bf16(a0, b0, acc[f], 0, 0, 0);
      acc[f] = __builtin_amdgcn_mfma_f32_16x16x32_bf16(a1, b1, acc[f], 0, 0, 0);
    }
    __syncthreads();
  }
}

// ---------------- input projection GEMM + bias + LN + relu ----------------
__global__ __launch_bounds__(256) void k_gemm_in(
    const float* __restrict__ x, const unsigned short* __restrict__ Wt,
    const float* __restrict__ b, const float* __restrict__ g,
    const float* __restrict__ be, float* __restrict__ h0) {
  __shared__ unsigned short lds_a[64 * 64];
  __shared__ unsigned short lds_b[128 * 64];
  f32x4 acc[8];
  size_t row0 = (size_t)blockIdx.x * 64;
  gemm_mainloop<IN_DIM>(x, row0, Wt, lds_a, lds_b, acc);

  int lane = threadIdx.x & 63, wid = threadIdx.x >> 6;
  int cbase = lane & 15;
  float s[4] = {0.f, 0.f, 0.f, 0.f}, q[4] = {0.f, 0.f, 0.f, 0.f};
  float gg[8], bb[8];
#pragma unroll
  for (int f = 0; f < 8; ++f) {
    int c = f * 16 + cbase;
    float bias = b[c];
    gg[f] = g[c]; bb[f] = be[c];
#pragma unroll
    for (int j = 0; j < 4; ++j) {
      float v = acc[f][j] + bias;
      acc[f][j] = v;
      s[j] += v; q[j] += v * v;
    }
  }
#pragma unroll
  for (int off = 8; off >= 1; off >>= 1)
#pragma unroll
    for (int j = 0; j < 4; ++j) {
      s[j] += __shfl_xor(s[j], off);
      q[j] += __shfl_xor(q[j], off);
    }
#pragma unroll
  for (int j = 0; j < 4; ++j) {
    size_t row = row0 + wid * 16 + (lane >> 4) * 4 + j;
    if (row < N_NODES) {
      float mu = s[j] * (1.f / 128.f);
      float var = q[j] * (1.f / 128.f) - mu * mu;
      float rs = rsqrtf(var + 1e-5f);
#pragma unroll
      for (int f = 0; f < 8; ++f) {
        float y = (acc[f][j] - mu) * rs * gg[f] + bb[f];
        h0[row * HID + f * 16 + cbase] = fmaxf(y, 0.f);
      }
    }
  }
}

// ---------------- GAT projection GEMM + hp(bf16) store + es/ed (pre-scaled by log2e) ----------------
__global__ __launch_bounds__(256) void k_gemm_gat(
    const float* __restrict__ h, const unsigned short* __restrict__ Wt,
    const float* __restrict__ asrc, const float* __restrict__ adst,
    unsigned short* __restrict__ hp_bf, float* __restrict__ es,
    float* __restrict__ ed) {
  __shared__ unsigned short lds_a[64 * 64];
  __shared__ unsigned short lds_b[128 * 64];
  f32x4 acc[8];
  size_t row0 = (size_t)blockIdx.x * 64;
  gemm_mainloop<HID>(h, row0, Wt, lds_a, lds_b, acc);

  int lane = threadIdx.x & 63, wid = threadIdx.x >> 6;
  int cbase = lane & 15;
#pragma unroll
  for (int f = 0; f < 8; ++f) {   // frag f == head f (cols f*16..f*16+15)
    float av = asrc[f * 16 + cbase], bv = adst[f * 16 + cbase];
    float eS[4], eD[4];
#pragma unroll
    for (int j = 0; j < 4; ++j) { eS[j] = acc[f][j] * av; eD[j] = acc[f][j] * bv; }
#pragma unroll
    for (int off = 8; off >= 1; off >>= 1)
#pragma unroll
      for (int j = 0; j < 4; ++j) {
        eS[j] += __shfl_xor(eS[j], off);
        eD[j] += __shfl_xor(eD[j], off);
      }
#pragma unroll
    for (int j = 0; j < 4; ++j) {
      size_t row = row0 + wid * 16 + (lane >> 4) * 4 + j;
      if (row < N_NODES) {
        hp_bf[row * HID + f * 16 + cbase] = f2bf(acc[f][j]);
        if (cbase == 0) {
          es[row * HEADS + f] = eS[j] * LOG2E;
          ed[row * HEADS + f] = eD[j] * LOG2E;
        }
      }
    }
  }
}

// ---------------- CSR build: count -> hierarchical scan (3 tiny kernels) -> scatter ----
__global__ void k_count(const int* __restrict__ dst, int* __restrict__ deg) {
  int e = blockIdx.x * blockDim.x + threadIdx.x;
  if (e < N_EDGES) atomicAdd(&deg[dst[e]], 1);
}

// A: per-block exclusive prefix of deg -> startv (block-local); blocksum[b] = block total
__global__ __launch_bounds__(256) void k_scan_local(
    const int* __restrict__ deg, int* __restrict__ startv,
    int* __restrict__ blocksum) {
  __shared__ int wsum[4];
  int tid = threadIdx.x, lane = tid & 63, wid = tid >> 6;
  int n = blockIdx.x * 256 + tid;
  int d = (n < N_NODES) ? deg[n] : 0;
  int v = d;
#pragma unroll
  for (int off = 1; off < 64; off <<= 1) {
    int t = __shfl_up(v, off);
    if (lane >= off) v += t;
  }
  if (lane == 63) wsum[wid] = v;
  __syncthreads();
  int prefix = 0;
  for (int w = 0; w < wid; ++w) prefix += wsum[w];
  int excl = prefix + v - d;
  if (n < N_NODES) startv[n] = excl;
  if (tid == 255) blocksum[blockIdx.x] = excl + d;
}

// B: exclusive scan of 196 block sums (single block)
__global__ __launch_bounds__(256) void k_scan_block(
    const int* __restrict__ blocksum, int* __restrict__ blockoffs) {
  __shared__ int wsum[4];
  int tid = threadIdx.x, lane = tid & 63, wid = tid >> 6;
  int d = (tid < NBLK) ? blocksum[tid] : 0;
  int v = d;
#pragma unroll
  for (int off = 1; off < 64; off <<= 1) {
    int t = __shfl_up(v, off);
    if (lane >= off) v += t;
  }
  if (lane == 63) wsum[wid] = v;
  __syncthreads();
  int prefix = 0;
  for (int w = 0; w < wid; ++w) prefix += wsum[w];
  if (tid < NBLK) blockoffs[tid] = prefix + v - d;
}

// C: startv[n] += blockoffs[block(n)]
__global__ __launch_bounds__(256) void k_scan_add(
    int* __restrict__ startv, const int* __restrict__ blockoffs) {
  int n = blockIdx.x * blockDim.x + threadIdx.x;
  if (n < N_NODES) startv[n] += blockoffs[blockIdx.x];
}

__global__ void k_scatter(const int* __restrict__ src, const int* __restrict__ dst,
                          const int* __restrict__ start, int* __restrict__ cur,
                          int* __restrict__ col) {
  int e = blockIdx.x * blockDim.x + threadIdx.x;
  if (e < N_EDGES) {
    int d = dst[e];
    int pos = start[d] + atomicAdd(&cur[d], 1);
    col[pos] = src[e];
  }
}

// ---------------- GAT aggregation: wave/node, 8-edge batched, 2-deep software pipeline ----
__global__ __launch_bounds__(256) void k_gat_agg(
    const unsigned short* __restrict__ hp_bf, const float* __restrict__ es,
    const float* __restrict__ ed, const int* __restrict__ start,
    const int* __restrict__ deg, const int* __restrict__ col,
    const float* __restrict__ bc, const float* __restrict__ gc,
    const float* __restrict__ bec, const float* __restrict__ h_res,
    float* __restrict__ h_out, int use_res) {
  int lane = threadIdx.x & 63;
  int n = blockIdx.x * 4 + (threadIdx.x >> 6);
  if (n >= N_NODES) return;
  int head = lane >> 3;
  int sub = lane & 7;
  int hbase = head * 8;
  const unsigned* hpu = (const unsigned*)hp_bf;  // 2 bf16 channels per uint

  float edv = ed[(size_t)n * HEADS + head];
  float z0 = es[(size_t)n * HEADS + head] + edv;
  z0 = fmaxf(z0, 0.2f * z0);            // leaky_relu (pre-scaled by log2e)
  float p0 = exp2f(z0);                 // self-loop weight
  unsigned su = hpu[(size_t)n * 64 + lane];

  float den0 = p0, ax0 = p0 * bflo(su), ay0 = p0 * bfhi(su);
  float den1 = 0.f, ax1 = 0.f, ay1 = 0.f;

  int s0 = start[n], s1 = s0 + deg[n];
  int nb = (s1 - s0) >> 3;
  int base = s0;
  int se = 0;
  float p = 0.f;
  if (nb > 0) {                          // prologue: batch 0 logits
    se = col[base + sub];
    float z = es[(size_t)se * HEADS + head] + edv;
    z = fmaxf(z, 0.2f * z);
    p = exp2f(z);
  }
  for (int t = 0; t < nb; ++t) {
    int seN = 0;
    bool more = (t + 1 < nb);
    if (more) seN = col[base + 8 + sub]; // issue next col load first
#pragma unroll
    for (int k = 0; k < 8; k += 2) {     // current batch hp gathers + accumulate
      float pk0 = __shfl(p, hbase + k);
      float pk1 = __shfl(p, hbase + k + 1);
      int sk0 = __shfl(se, k);
      int sk1 = __shfl(se, k + 1);
      unsigned h0 = hpu[(size_t)sk0 * 64 + lane];
      unsigned h1 = hpu[(size_t)sk1 * 64 + lane];
      den0 += pk0;
      ax0 = fmaf(pk0, bflo(h0), ax0);
      ay0 = fmaf(pk0, bfhi(h0), ay0);
      den1 += pk1;
      ax1 = fmaf(pk1, bflo(h1), ax1);
      ay1 = fmaf(pk1, bfhi(h1), ay1);
    }
    if (more) {                          // next batch logits (overlapped with hp waits)
      float zN = es[(size_t)seN * HEADS + head] + edv;
      zN = fmaxf(zN, 0.2f * zN);
      p = exp2f(zN);
      se = seN;
    }
    base += 8;
  }
  int rem = s1 - base;
  if (rem > 0) {
    int e = base + (sub < rem ? sub : rem - 1);
    int set = col[e];
    float z = es[(size_t)set * HEADS + head] + edv;
    z = fmaxf(z, 0.2f * z);
    float pt = (sub < rem) ? exp2f(z) : 0.f;
    for (int k = 0; k < rem; ++k) {
      float pk = __shfl(pt, hbase + k);
      int sk = __shfl(set, k);
      unsigned hk = hpu[(size_t)sk * 64 + lane];
      den0 += pk;
      ax0 = fmaf(pk, bflo(hk), ax0);
      ay0 = fmaf(pk, bfhi(hk), ay0);
    }
  }
  float den = den0 + den1 + 1e-16f;
  float rden = 1.f / den;
  float v0 = (ax0 + ax1) * rden + bc[2 * lane];
  float v1 = (ay0 + ay1) * rden + bc[2 * lane + 1];

  float s = v0 + v1, q = v0 * v0 + v1 * v1;
#pragma unroll
  for (int off = 32; off >= 1; off >>= 1) {
    s += __shfl_xor(s, off);
    q += __shfl_xor(q, off);
  }
  float mu = s * (1.f / 128.f);
  float var = q * (1.f / 128.f) - mu * mu;
  float rs = rsqrtf(var + 1e-5f);
  float y0 = fmaxf((v0 - mu) * rs * gc[2 * lane] + bec[2 * lane], 0.f);
  float y1 = fmaxf((v1 - mu) * rs * gc[2 * lane + 1] + bec[2 * lane + 1], 0.f);
  if (use_res) {
    float2 r = ((const float2*)h_res)[(size_t)n * 64 + lane];
    y0 += r.x; y1 += r.y;
  }
  ((float2*)h_out)[(size_t)n * 64 + lane] = make_float2(y0, y1);
}

// ---------------- classifier head: fused 3-stage MFMA MLP ----------------
__global__ __launch_bounds__(256) void k_head_mfma(
    const float* __restrict__ h,
    const unsigned short* __restrict__ W1t, const float* __restrict__ b1,
    const float* __restrict__ g1, const float* __restrict__ be1,
    const unsigned short* __restrict__ W2t, const float* __restrict__ b2,
    const float* __restrict__ g2, const float* __restrict__ be2,
    const unsigned short* __restrict__ W3t, const float* __restrict__ b3,
    float* __restrict__ out) {
  __shared__ unsigned short lds_a[64 * 128];
  __shared__ unsigned short lds_b1[64 * 128];
  __shared__ unsigned short lds_h1[64 * 64];
  __shared__ unsigned short lds_b2[32 * 64];
  __shared__ unsigned short lds_h2[64 * 32];
  __shared__ unsigned short lds_b3[16 * 32];
  int tid = threadIdx.x, lane = tid & 63, wid = tid >> 6;
  size_t row0 = (size_t)blockIdx.x * 64;

#pragma unroll
  for (int jj = 0; jj < 8; ++jj) {
    int i = tid + jj * 256;
    int r = i >> 5, kq = (i & 31) * 4;
    size_t rg = row0 + r;
    if (rg >= N_NODES) rg = N_NODES - 1;
    float4 v = *(const float4*)(h + rg * HID + kq);
    short4v b4;
    b4[0] = (short)f2bf(v.x); b4[1] = (short)f2bf(v.y);
    b4[2] = (short)f2bf(v.z); b4[3] = (short)f2bf(v.w);
    int idx = (r * 128 + kq) ^ ((r & 7) << 3);
    *(short4v*)&lds_a[idx] = b4;
  }
#pragma unroll
  for (int jj = 0; jj < 4; ++jj) {
    int i = tid + jj * 256;
    int c = i >> 4, kq = (i & 15) * 8;
    short8 w = *(const short8*)(W1t + c * 128 + kq);
    int idx = (c * 128 + kq) ^ ((c & 7) << 3);
    *(short8*)&lds_b1[idx] = w;
  }
  {
    int c = tid >> 3, kq = (tid & 7) * 8;
    if (c < 32) {
      short8 w = *(const short8*)(W2t + c * 64 + kq);
      int idx = (c * 64 + kq) ^ ((c & 7) << 3);
      *(short8*)&lds_b2[idx] = w;
    }
  }
  if (tid < 64) {
    int c = tid >> 2, kq = (tid & 3) * 8;
    short8 w = *(const short8*)(W3t + c * 32 + kq);
    int idx = (c * 32 + kq) ^ ((c & 3) << 3);
    *(short8*)&lds_b3[idx] = w;
  }
  __syncthreads();

  int arow = wid * 16 + (lane & 15);
  int kq8 = (lane >> 4) * 8;
  int cbase = lane & 15;

  // ---- stage 1: 128 -> 64 ----
  f32x4 acc1[4];
#pragma unroll
  for (int f = 0; f < 4; ++f)
#pragma unroll
    for (int j = 0; j < 4; ++j) acc1[f][j] = 0.f;
  {
    short8 a0 = *(short8*)&lds_a[(arow * 128 + kq8) ^ ((arow & 7) << 3)];
    short8 a1 = *(short8*)&lds_a[(arow * 128 + 32 + kq8) ^ ((arow & 7) << 3)];
    short8 a2 = *(short8*)&lds_a[(arow * 128 + 64 + kq8) ^ ((arow & 7) << 3)];
    short8 a3 = *(short8*)&lds_a[(arow * 128 + 96 + kq8) ^ ((arow & 7) << 3)];
#pragma unroll
    for (int f = 0; f < 4; ++f) {
      int c = f * 16 + cbase;
      short8 b0 = *(short8*)&lds_b1[(c * 128 + kq8) ^ ((c & 7) << 3)];
      short8 bb1 = *(short8*)&lds_b1[(c * 128 + 32 + kq8) ^ ((c & 7) << 3)];
      short8 b2v = *(short8*)&lds_b1[(c * 128 + 64 + kq8) ^ ((c & 7) << 3)];
      short8 b3v = *(short8*)&lds_b1[(c * 128 + 96 + kq8) ^ ((c & 7) << 3)];
      acc1[f] = __builtin_amdgcn_mfma_f32_16x16x32_bf16(a0, b0, acc1[f], 0, 0, 0);
      acc1[f] = __builtin_amdgcn_mfma_f32_16x16x32_bf16(a1, bb1, acc1[f], 0, 0, 0);
      acc1[f] = __builtin_amdgcn_mfma_f32_16x16x32_bf16(a2, b2v, acc1[f], 0, 0, 0);
      acc1[f] = __builtin_amdgcn_mfma_f32_16x16x32_bf16(a3, b3v, acc1[f], 0, 0, 0);
    }
  }
  {
    float s[4] = {0, 0, 0, 0}, q[4] = {0, 0, 0, 0};
#pragma unroll
    for (int f = 0; f < 4; ++f) {
      int c = f * 16 + cbase;
      float bias = b1[c];
#pragma unroll
      for (int j = 0; j < 4; ++j) {
        float v = acc1[f][j] + bias;
        acc1[f][j] = v;
        s[j] += v; q[j] += v * v;
      }
    }
#pragma unroll
    for (int off = 8; off >= 1; off >>= 1)
#pragma unroll
      for (int j = 0; j < 4; ++j) {
        s[j] += __shfl_xor(s[j], off);
        q[j] += __shfl_xor(q[j], off);
      }
#pragma unroll
    for (int j = 0; j < 4; ++j) {
      int row = wid * 16 + (lane >> 4) * 4 + j;
      float mu = s[j] * (1.f / 64.f);
      float var = q[j] * (1.f / 64.f) - mu * mu;
      float rs = rsqrtf(var + 1e-5f);
#pragma unroll
      for (int f = 0; f < 4; ++f) {
        int c = f * 16 + cbase;
        float y = fmaxf((acc1[f][j] - mu) * rs * g1[c] + be1[c], 0.f);
        lds_h1[(row * 64 + c) ^ ((row & 7) << 3)] = f2bf(y);
      }
    }
  }
  __syncthreads();

  // ---- stage 2: 64 -> 32 ----
  f32x4 acc2[2];
#pragma unroll
  for (int f = 0; f < 2; ++f)
#pragma unroll
    for (int j = 0; j < 4; ++j) acc2[f][j] = 0.f;
  {
    short8 a0 = *(short8*)&lds_h1[(arow * 64 + kq8) ^ ((arow & 7) << 3)];
    short8 a1 = *(short8*)&lds_h1[(arow * 64 + 32 + kq8) ^ ((arow & 7) << 3)];
#pragma unroll
    for (int f = 0; f < 2; ++f) {
      int c = f * 16 + cbase;
      short8 b0 = *(short8*)&lds_b2[(c * 64 + kq8) ^ ((c & 7) << 3)];
      short8 bb1 = *(short8*)&lds_b2[(c * 64 + 32 + kq8) ^ ((c & 7) << 3)];
      acc2[f] = __builtin_amdgcn_mfma_f32_16x16x32_bf16(a0, b0, acc2[f], 0, 0, 0);
      acc2[f] = __builtin_amdgcn_mfma_f32_16x16x32_bf16(a1, bb1, acc2[f], 0, 0, 0);
    }
  }
  {
    float s[4] = {0, 0, 0, 0}, q[4] = {0, 0, 0, 0};
#pragma unroll
    for (int f = 0; f < 2; ++f) {
      int c = f * 16 + cbase;
      float bias = b2[c];
#pragma unroll
      for (int j = 0; j < 4; ++j) {
        float v = acc2[f][j] + bias;
        acc2[f][j] = v;
        s[j] += v; q[j] += v * v;
      }
    }
#pragma unroll
    for (int off = 8; off >= 1; off >>= 1)
#pragma unroll
      for (int j = 0; j < 4; ++j) {
        s[j] += __shfl_xor(s[j], off);
        q[j] += __shfl_xor(q[j], off);
      }
#pragma unroll
    for (int j = 0; j < 4; ++j) {
      int row = wid * 16 + (lane >> 4) * 4 + j;
      float mu = s[j] * (1.f / 32.f);
      float var = q[j] * (1.f / 32.f) - mu * mu;
      float rs = rsqrtf(var + 1e-5f);
#pragma unroll
      for (int f = 0; f < 2; ++f) {
        int c = f * 16 + cbase;
        float y = fmaxf((acc2[f][j] - mu) * rs * g2[c] + be2[c], 0.f);
        lds_h2[(row * 32 + c) ^ ((row & 3) << 3)] = f2bf(y);
      }
    }
  }
  __syncthreads();

  // ---- stage 3: 32 -> 8 (cols padded to 16) ----
  f32x4 acc3;
#pragma unroll
  for (int j = 0; j < 4; ++j) acc3[j] = 0.f;
  {
    short8 a = *(short8*)&lds_h2[(arow * 32 + kq8) ^ ((arow & 3) << 3)];
    short8 b = *(short8*)&lds_b3[(cbase * 32 + kq8) ^ ((cbase & 3) << 3)];
    acc3 = __builtin_amdgcn_mfma_f32_16x16x32_bf16(a, b, acc3, 0, 0, 0);
  }
  if (cbase < N_CLASSES) {
    float bias = b3[cbase];
#pragma unroll
    for (int j = 0; j < 4; ++j) {
      size_t row = row0 + wid * 16 + (lane >> 4) * 4 + j;
      if (row < N_NODES) out[row * N_CLASSES + cbase] = acc3[j] + bias;
    }
  }
}

// ---------------- launch ----------------
extern "C" void kernel_launch(void* const* d_in, const int* in_sizes, int n_in,
                              void* d_out, int out_size, void* d_ws, size_t ws_size,
                              hipStream_t stream) {
  const float* x     = (const float*)d_in[0];
  const int*   esrc  = (const int*)d_in[1];
  const int*   edst  = (const int*)d_in[2];
  const float* W_in  = (const float*)d_in[3];
  const float* b_in  = (const float*)d_in[4];
  const float* g_in  = (const float*)d_in[5];
  const float* be_in = (const float*)d_in[6];
  const float* Wc    = (const float*)d_in[7];
  const float* a_src = (const float*)d_in[8];
  const float* a_dst = (const float*)d_in[9];
  const float* bc    = (const float*)d_in[10];
  const float* gc    = (const float*)d_in[11];
  const float* bec   = (const float*)d_in[12];
  const float* W1    = (const float*)d_in[13];
  const float* b1    = (const float*)d_in[14];
  const float* g1    = (const float*)d_in[15];
  const float* be1   = (const float*)d_in[16];
  const float* W2    = (const float*)d_in[17];
  const float* b2    = (const float*)d_in[18];
  const float* g2    = (const float*)d_in[19];
  const float* be2   = (const float*)d_in[20];
  const float* W3    = (const float*)d_in[21];
  const float* b3    = (const float*)d_in[22];

  float* ws = (float*)d_ws;
  const size_t NH = (size_t)N_NODES * HID;
  float* hA = ws;
  float* hB = hA + NH;
  float* es = hB + NH;
  float* ed = es + (size_t)N_NODES * HEADS;
  unsigned short* hp_bf = (unsigned short*)(ed + (size_t)N_NODES * HEADS);
  int* deg    = (int*)(hp_bf + NH);
  int* cur    = deg + N_NODES;
  int* startv = cur + N_NODES;
  int* blocksum  = startv + N_NODES;
  int* blockoffs = blocksum + NBLK;
  int* col    = blockoffs + NBLK;
  uintptr_t wp = (uintptr_t)(col + N_EDGES);
  wp = (wp + 15) & ~(uintptr_t)15;
  unsigned short* Wt_in = (unsigned short*)wp;
  unsigned short* Wt_c  = Wt_in + (size_t)IN_DIM * HID;
  unsigned short* W1t   = Wt_c + (size_t)N_LAYERS * HID * HID;
  unsigned short* W2t   = W1t + 64 * 128;
  unsigned short* W3t   = W2t + 32 * 64;

  // weights -> bf16 transposed + zero deg/cur (merged)
  k_prep<<<(2 * N_NODES + 255) / 256, 256, 0, stream>>>(
      W_in, Wc, W1, W2, W3, Wt_in, Wt_c, W1t, W2t, W3t, deg);

  // input projection + LN + relu (MFMA)
  k_gemm_in<<<(N_NODES + 63) / 64, 256, 0, stream>>>(x, Wt_in, b_in, g_in, be_in, hA);

  // CSR build: count -> hierarchical scan -> scatter
  k_count<<<(N_EDGES + 255) / 256, 256, 0, stream>>>(edst, deg);
  k_scan_local<<<NBLK, 256, 0, stream>>>(deg, startv, blocksum);
  k_scan_block<<<1, 256, 0, stream>>>(blocksum, blockoffs);
  k_scan_add<<<NBLK, 256, 0, stream>>>(startv, blockoffs);
  k_scatter<<<(N_EDGES + 255) / 256, 256, 0, stream>>>(esrc, edst, startv, cur, col);

  float* hcur = hA;
  float* hnext = hB;
  for (int l = 0; l < N_LAYERS; ++l) {
    k_gemm_gat<<<(N_NODES + 63) / 64, 256, 0, stream>>>(
        hcur, Wt_c + (size_t)l * HID * HID,
        a_src + (size_t)l * HEADS * HEAD_DIM, a_dst + (size_t)l * HEADS * HEAD_DIM,
        hp_bf, es, ed);
    k_gat_agg<<<(N_NODES + 3) / 4, 256, 0, stream>>>(
        hp_bf, es, ed, startv, deg, col,
        bc + (size_t)l * HID, gc + (size_t)l * HID, bec + (size_t)l * HID,
        hcur, hnext, l > 0 ? 1 : 0);
    float* t = hcur; hcur = hnext; hnext = t;
  }

  k_head_mfma<<<(N_NODES + 63) / 64, 256, 0, stream>>>(
      hcur, W1t, b1, g1, be1, W2t, b2, g2, be2, W3t, b3, (float*)d_out);
}

// Round 14
// 331.137 us; speedup vs baseline: 1.5659x; 1.0217x over previous
//
#include <hip/hip_runtime.h>
#include <math.h>

#define N_NODES 50000
#define N_EDGES 800000
#define IN_DIM 512
#define HID 128
#define HEADS 8
#define HEAD_DIM 16
#define N_LAYERS 3
#define N_CLASSES 8
#define LOG2E 1.4426950408889634f
#define NBLK 196  // ceil(N_NODES/256)

typedef __attribute__((ext_vector_type(8))) short short8;
typedef __attribute__((ext_vector_type(4))) short short4v;
typedef __attribute__((ext_vector_type(4))) float f32x4;

__device__ inline unsigned short f2bf(float f) {
  unsigned u = __float_as_uint(f);
  u = (u + 0x7fffu + ((u >> 16) & 1u)) >> 16;
  return (unsigned short)u;
}
__device__ inline float bflo(unsigned u) { return __uint_as_float(u << 16); }
__device__ inline float bfhi(unsigned u) { return __uint_as_float(u & 0xffff0000u); }

// ---------------- prep: weight fp32->bf16 transpose + zero deg/cur ----------------
__global__ __launch_bounds__(256) void k_prep(
    const float* __restrict__ W_in, const float* __restrict__ Wc,
    const float* __restrict__ W1, const float* __restrict__ W2,
    const float* __restrict__ W3,
    unsigned short* __restrict__ Wt_in, unsigned short* __restrict__ Wt_c,
    unsigned short* __restrict__ W1t, unsigned short* __restrict__ W2t,
    unsigned short* __restrict__ W3t, int* __restrict__ degcur) {
  int i = blockIdx.x * blockDim.x + threadIdx.x;
  if (i < 2 * N_NODES) degcur[i] = 0;
  if (i < IN_DIM * HID) {                      // Wt_in[c][k]
    int c = i >> 9, k = i & 511;
    Wt_in[i] = f2bf(W_in[k * HID + c]);
  }
  if (i < N_LAYERS * HID * HID) {              // Wt_c[l][c][k]
    int l = i >> 14, r = i & 16383, c = r >> 7, k = r & 127;
    Wt_c[i] = f2bf(Wc[l * HID * HID + k * HID + c]);
  }
  if (i < 64 * 128) {                          // W1t[c][k]
    int c = i >> 7, k = i & 127;
    W1t[i] = f2bf(W1[k * 64 + c]);
  }
  if (i < 32 * 64) {                           // W2t[c][k]
    int c = i >> 6, k = i & 63;
    W2t[i] = f2bf(W2[k * 32 + c]);
  }
  if (i < 16 * 32) {                           // W3t[c][k], cols 8..15 zero-padded
    int c = i >> 5, k = i & 31;
    W3t[i] = (c < 8) ? f2bf(W3[k * N_CLASSES + c]) : 0;
  }
}

// ---------------- MFMA GEMM mainloop: C[64 x 128] += A[64 x K] @ W_bf16t --------------
// ABF=false: A is fp32 (converted during staging); ABF=true: A is bf16 (direct copy).
template <int K, bool ABF>
__device__ inline void gemm_mainloop(const void* __restrict__ Av, size_t row0,
                                     const unsigned short* __restrict__ Wt,
                                     unsigned short* lds_a, unsigned short* lds_b,
                                     f32x4 acc[8]) {
  const int tid = threadIdx.x;
  const int lane = tid & 63, wid = tid >> 6;
#pragma unroll
  for (int f = 0; f < 8; ++f)
#pragma unroll
    for (int j = 0; j < 4; ++j) acc[f][j] = 0.f;

  for (int kb = 0; kb < K; kb += 64) {
    if (ABF) {
      const unsigned short* A = (const unsigned short*)Av;
#pragma unroll
      for (int j = 0; j < 2; ++j) {
        int i = tid + j * 256;
        int r = i >> 3, kq = (i & 7) * 8;
        size_t rg = row0 + r;
        if (rg >= N_NODES) rg = N_NODES - 1;
        short8 v = *(const short8*)(A + rg * K + kb + kq);
        int idx = (r * 64 + kq) ^ ((r & 7) << 3);
        *(short8*)&lds_a[idx] = v;
      }
    } else {
      const float* A = (const float*)Av;
#pragma unroll
      for (int j = 0; j < 4; ++j) {
        int i = tid + j * 256;
        int r = i >> 4, kq = (i & 15) * 4;
        size_t rg = row0 + r;
        if (rg >= N_NODES) rg = N_NODES - 1;
        float4 v = *(const float4*)(A + rg * K + kb + kq);
        short4v b4;
        b4[0] = (short)f2bf(v.x); b4[1] = (short)f2bf(v.y);
        b4[2] = (short)f2bf(v.z); b4[3] = (short)f2bf(v.w);
        int idx = (r * 64 + kq) ^ ((r & 7) << 3);
        *(short4v*)&lds_a[idx] = b4;
      }
    }
#pragma unroll
    for (int j = 0; j < 4; ++j) {
      int i = tid + j * 256;
      int c = i >> 3, kq = (i & 7) * 8;
      short8 w = *(const short8*)(Wt + (size_t)c * K + kb + kq);
      int idx = (c * 64 + kq) ^ ((c & 7) << 3);
      *(short8*)&lds_b[idx] = w;
    }
    __syncthreads();

    int arow = wid * 16 + (lane & 15);
    int kq8 = (lane >> 4) * 8;
    short8 a0 = *(short8*)&lds_a[(arow * 64 + kq8) ^ ((arow & 7) << 3)];
    short8 a1 = *(short8*)&lds_a[(arow * 64 + 32 + kq8) ^ ((arow & 7) << 3)];
#pragma unroll
    for (int f = 0; f < 8; ++f) {
      int c = f * 16 + (lane & 15);
      short8 b0 = *(short8*)&lds_b[(c * 64 + kq8) ^ ((c & 7) << 3)];
      short8 b1 = *(short8*)&lds_b[(c * 64 + 32 + kq8) ^ ((c & 7) << 3)];
      acc[f] = __builtin_amdgcn_mfma_f32_16x16x32_bf16(a0, b0, acc[f], 0, 0, 0);
      acc[f] = __builtin_amdgcn_mfma_f32_16x16x32_bf16(a1, b1, acc[f], 0, 0, 0);
    }
    __syncthreads();
  }
}

// ---------------- input projection GEMM + bias + LN + relu -> h bf16 ----------------
__global__ __launch_bounds__(256) void k_gemm_in(
    const float* __restrict__ x, const unsigned short* __restrict__ Wt,
    const float* __restrict__ b, const float* __restrict__ g,
    const float* __restrict__ be, unsigned short* __restrict__ h0) {
  __shared__ unsigned short lds_a[64 * 64];
  __shared__ unsigned short lds_b[128 * 64];
  f32x4 acc[8];
  size_t row0 = (size_t)blockIdx.x * 64;
  gemm_mainloop<IN_DIM, false>(x, row0, Wt, lds_a, lds_b, acc);

  int lane = threadIdx.x & 63, wid = threadIdx.x >> 6;
  int cbase = lane & 15;
  float s[4] = {0.f, 0.f, 0.f, 0.f}, q[4] = {0.f, 0.f, 0.f, 0.f};
  float gg[8], bb[8];
#pragma unroll
  for (int f = 0; f < 8; ++f) {
    int c = f * 16 + cbase;
    float bias = b[c];
    gg[f] = g[c]; bb[f] = be[c];
#pragma unroll
    for (int j = 0; j < 4; ++j) {
      float v = acc[f][j] + bias;
      acc[f][j] = v;
      s[j] += v; q[j] += v * v;
    }
  }
#pragma unroll
  for (int off = 8; off >= 1; off >>= 1)
#pragma unroll
    for (int j = 0; j < 4; ++j) {
      s[j] += __shfl_xor(s[j], off);
      q[j] += __shfl_xor(q[j], off);
    }
#pragma unroll
  for (int j = 0; j < 4; ++j) {
    size_t row = row0 + wid * 16 + (lane >> 4) * 4 + j;
    if (row < N_NODES) {
      float mu = s[j] * (1.f / 128.f);
      float var = q[j] * (1.f / 128.f) - mu * mu;
      float rs = rsqrtf(var + 1e-5f);
#pragma unroll
      for (int f = 0; f < 8; ++f) {
        float y = (acc[f][j] - mu) * rs * gg[f] + bb[f];
        h0[row * HID + f * 16 + cbase] = f2bf(fmaxf(y, 0.f));
      }
    }
  }
}

// ---------------- GAT projection GEMM (bf16 h in) + hp(bf16) + es/ed ----------------
__global__ __launch_bounds__(256) void k_gemm_gat(
    const unsigned short* __restrict__ h, const unsigned short* __restrict__ Wt,
    const float* __restrict__ asrc, const float* __restrict__ adst,
    unsigned short* __restrict__ hp_bf, float* __restrict__ es,
    float* __restrict__ ed) {
  __shared__ unsigned short lds_a[64 * 64];
  __shared__ unsigned short lds_b[128 * 64];
  f32x4 acc[8];
  size_t row0 = (size_t)blockIdx.x * 64;
  gemm_mainloop<HID, true>(h, row0, Wt, lds_a, lds_b, acc);

  int lane = threadIdx.x & 63, wid = threadIdx.x >> 6;
  int cbase = lane & 15;
#pragma unroll
  for (int f = 0; f < 8; ++f) {   // frag f == head f (cols f*16..f*16+15)
    float av = asrc[f * 16 + cbase], bv = adst[f * 16 + cbase];
    float eS[4], eD[4];
#pragma unroll
    for (int j = 0; j < 4; ++j) { eS[j] = acc[f][j] * av; eD[j] = acc[f][j] * bv; }
#pragma unroll
    for (int off = 8; off >= 1; off >>= 1)
#pragma unroll
      for (int j = 0; j < 4; ++j) {
        eS[j] += __shfl_xor(eS[j], off);
        eD[j] += __shfl_xor(eD[j], off);
      }
#pragma unroll
    for (int j = 0; j < 4; ++j) {
      size_t row = row0 + wid * 16 + (lane >> 4) * 4 + j;
      if (row < N_NODES) {
        hp_bf[row * HID + f * 16 + cbase] = f2bf(acc[f][j]);
        if (cbase == 0) {
          es[row * HEADS + f] = eS[j] * LOG2E;
          ed[row * HEADS + f] = eD[j] * LOG2E;
        }
      }
    }
  }
}

// ---------------- CSR build: count -> hierarchical scan (3 tiny kernels) -> scatter ----
__global__ void k_count(const int* __restrict__ dst, int* __restrict__ deg) {
  int e = blockIdx.x * blockDim.x + threadIdx.x;
  if (e < N_EDGES) atomicAdd(&deg[dst[e]], 1);
}

__global__ __launch_bounds__(256) void k_scan_local(
    const int* __restrict__ deg, int* __restrict__ startv,
    int* __restrict__ blocksum) {
  __shared__ int wsum[4];
  int tid = threadIdx.x, lane = tid & 63, wid = tid >> 6;
  int n = blockIdx.x * 256 + tid;
  int d = (n < N_NODES) ? deg[n] : 0;
  int v = d;
#pragma unroll
  for (int off = 1; off < 64; off <<= 1) {
    int t = __shfl_up(v, off);
    if (lane >= off) v += t;
  }
  if (lane == 63) wsum[wid] = v;
  __syncthreads();
  int prefix = 0;
  for (int w = 0; w < wid; ++w) prefix += wsum[w];
  int excl = prefix + v - d;
  if (n < N_NODES) startv[n] = excl;
  if (tid == 255) blocksum[blockIdx.x] = excl + d;
}

__global__ __launch_bounds__(256) void k_scan_block(
    const int* __restrict__ blocksum, int* __restrict__ blockoffs) {
  __shared__ int wsum[4];
  int tid = threadIdx.x, lane = tid & 63, wid = tid >> 6;
  int d = (tid < NBLK) ? blocksum[tid] : 0;
  int v = d;
#pragma unroll
  for (int off = 1; off < 64; off <<= 1) {
    int t = __shfl_up(v, off);
    if (lane >= off) v += t;
  }
  if (lane == 63) wsum[wid] = v;
  __syncthreads();
  int prefix = 0;
  for (int w = 0; w < wid; ++w) prefix += wsum[w];
  if (tid < NBLK) blockoffs[tid] = prefix + v - d;
}

__global__ __launch_bounds__(256) void k_scan_add(
    int* __restrict__ startv, const int* __restrict__ blockoffs) {
  int n = blockIdx.x * blockDim.x + threadIdx.x;
  if (n < N_NODES) startv[n] += blockoffs[blockIdx.x];
}

__global__ void k_scatter(const int* __restrict__ src, const int* __restrict__ dst,
                          const int* __restrict__ start, int* __restrict__ cur,
                          int* __restrict__ col) {
  int e = blockIdx.x * blockDim.x + threadIdx.x;
  if (e < N_EDGES) {
    int d = dst[e];
    int pos = start[d] + atomicAdd(&cur[d], 1);
    col[pos] = src[e];
  }
}

// ---------------- GAT aggregation: wave/node, 8-edge batched, 2-deep pipeline ---------
// h_res/h_out are packed bf16 (2 ch per uint).
__global__ __launch_bounds__(256) void k_gat_agg(
    const unsigned short* __restrict__ hp_bf, const float* __restrict__ es,
    const float* __restrict__ ed, const int* __restrict__ start,
    const int* __restrict__ deg, const int* __restrict__ col,
    const float* __restrict__ bc, const float* __restrict__ gc,
    const float* __restrict__ bec, const unsigned* __restrict__ h_res,
    unsigned* __restrict__ h_out, int use_res) {
  int lane = threadIdx.x & 63;
  int n = blockIdx.x * 4 + (threadIdx.x >> 6);
  if (n >= N_NODES) return;
  int head = lane >> 3;
  int sub = lane & 7;
  int hbase = head * 8;
  const unsigned* hpu = (const unsigned*)hp_bf;  // 2 bf16 channels per uint

  float edv = ed[(size_t)n * HEADS + head];
  float z0 = es[(size_t)n * HEADS + head] + edv;
  z0 = fmaxf(z0, 0.2f * z0);            // leaky_relu (pre-scaled by log2e)
  float p0 = exp2f(z0);                 // self-loop weight
  unsigned su = hpu[(size_t)n * 64 + lane];

  float den0 = p0, ax0 = p0 * bflo(su), ay0 = p0 * bfhi(su);
  float den1 = 0.f, ax1 = 0.f, ay1 = 0.f;

  int s0 = start[n], s1 = s0 + deg[n];
  int nb = (s1 - s0) >> 3;
  int base = s0;
  int se = 0;
  float p = 0.f;
  if (nb > 0) {                          // prologue: batch 0 logits
    se = col[base + sub];
    float z = es[(size_t)se * HEADS + head] + edv;
    z = fmaxf(z, 0.2f * z);
    p = exp2f(z);
  }
  for (int t = 0; t < nb; ++t) {
    int seN = 0;
    bool more = (t + 1 < nb);
    if (more) seN = col[base + 8 + sub]; // issue next col load first
#pragma unroll
    for (int k = 0; k < 8; k += 2) {     // current batch hp gathers + accumulate
      float pk0 = __shfl(p, hbase + k);
      float pk1 = __shfl(p, hbase + k + 1);
      int sk0 = __shfl(se, k);
      int sk1 = __shfl(se, k + 1);
      unsigned h0 = hpu[(size_t)sk0 * 64 + lane];
      unsigned h1 = hpu[(size_t)sk1 * 64 + lane];
      den0 += pk0;
      ax0 = fmaf(pk0, bflo(h0), ax0);
      ay0 = fmaf(pk0, bfhi(h0), ay0);
      den1 += pk1;
      ax1 = fmaf(pk1, bflo(h1), ax1);
      ay1 = fmaf(pk1, bfhi(h1), ay1);
    }
    if (more) {                          // next batch logits (overlapped with hp waits)
      float zN = es[(size_t)seN * HEADS + head] + edv;
      zN = fmaxf(zN, 0.2f * zN);
      p = exp2f(zN);
      se = seN;
    }
    base += 8;
  }
  int rem = s1 - base;
  if (rem > 0) {
    int e = base + (sub < rem ? sub : rem - 1);
    int set = col[e];
    float z = es[(size_t)set * HEADS + head] + edv;
    z = fmaxf(z, 0.2f * z);
    float pt = (sub < rem) ? exp2f(z) : 0.f;
    for (int k = 0; k < rem; ++k) {
      float pk = __shfl(pt, hbase + k);
      int sk = __shfl(set, k);
      unsigned hk = hpu[(size_t)sk * 64 + lane];
      den0 += pk;
      ax0 = fmaf(pk, bflo(hk), ax0);
      ay0 = fmaf(pk, bfhi(hk), ay0);
    }
  }
  float den = den0 + den1 + 1e-16f;
  float rden = 1.f / den;
  float v0 = (ax0 + ax1) * rden + bc[2 * lane];
  float v1 = (ay0 + ay1) * rden + bc[2 * lane + 1];

  float s = v0 + v1, q = v0 * v0 + v1 * v1;
#pragma unroll
  for (int off = 32; off >= 1; off >>= 1) {
    s += __shfl_xor(s, off);
    q += __shfl_xor(q, off);
  }
  float mu = s * (1.f / 128.f);
  float var = q * (1.f / 128.f) - mu * mu;
  float rs = rsqrtf(var + 1e-5f);
  float y0 = fmaxf((v0 - mu) * rs * gc[2 * lane] + bec[2 * lane], 0.f);
  float y1 = fmaxf((v1 - mu) * rs * gc[2 * lane + 1] + bec[2 * lane + 1], 0.f);
  if (use_res) {
    unsigned r = h_res[(size_t)n * 64 + lane];
    y0 += bflo(r); y1 += bfhi(r);
  }
  h_out[(size_t)n * 64 + lane] = (unsigned)f2bf(y0) | ((unsigned)f2bf(y1) << 16);
}

// ---------------- classifier head: fused 3-stage MFMA MLP (bf16 h in) ----------------
__global__ __launch_bounds__(256) void k_head_mfma(
    const unsigned short* __restrict__ h,
    const unsigned short* __restrict__ W1t, const float* __restrict__ b1,
    const float* __restrict__ g1, const float* __restrict__ be1,
    const unsigned short* __restrict__ W2t, const float* __restrict__ b2,
    const float* __restrict__ g2, const float* __restrict__ be2,
    const unsigned short* __restrict__ W3t, const float* __restrict__ b3,
    float* __restrict__ out) {
  __shared__ unsigned short lds_a[64 * 128];
  __shared__ unsigned short lds_b1[64 * 128];
  __shared__ unsigned short lds_h1[64 * 64];
  __shared__ unsigned short lds_b2[32 * 64];
  __shared__ unsigned short lds_h2[64 * 32];
  __shared__ unsigned short lds_b3[16 * 32];
  int tid = threadIdx.x, lane = tid & 63, wid = tid >> 6;
  size_t row0 = (size_t)blockIdx.x * 64;

#pragma unroll
  for (int jj = 0; jj < 4; ++jj) {
    int i = tid + jj * 256;
    int r = i >> 4, kq = (i & 15) * 8;
    size_t rg = row0 + r;
    if (rg >= N_NODES) rg = N_NODES - 1;
    short8 v = *(const short8*)(h + rg * HID + kq);
    int idx = (r * 128 + kq) ^ ((r & 7) << 3);
    *(short8*)&lds_a[idx] = v;
  }
#pragma unroll
  for (int jj = 0; jj < 4; ++jj) {
    int i = tid + jj * 256;
    int c = i >> 4, kq = (i & 15) * 8;
    short8 w = *(const short8*)(W1t + c * 128 + kq);
    int idx = (c * 128 + kq) ^ ((c & 7) << 3);
    *(short8*)&lds_b1[idx] = w;
  }
  {
    int c = tid >> 3, kq = (tid & 7) * 8;
    if (c < 32) {
      short8 w = *(const short8*)(W2t + c * 64 + kq);
      int idx = (c * 64 + kq) ^ ((c & 7) << 3);
      *(short8*)&lds_b2[idx] = w;
    }
  }
  if (tid < 64) {
    int c = tid >> 2, kq = (tid & 3) * 8;
    short8 w = *(const short8*)(W3t + c * 32 + kq);
    int idx = (c * 32 + kq) ^ ((c & 3) << 3);
    *(short8*)&lds_b3[idx] = w;
  }
  __syncthreads();

  int arow = wid * 16 + (lane & 15);
  int kq8 = (lane >> 4) * 8;
  int cbase = lane & 15;

  // ---- stage 1: 128 -> 64 ----
  f32x4 acc1[4];
#pragma unroll
  for (int f = 0; f < 4; ++f)
#pragma unroll
    for (int j = 0; j < 4; ++j) acc1[f][j] = 0.f;
  {
    short8 a0 = *(short8*)&lds_a[(arow * 128 + kq8) ^ ((arow & 7) << 3)];
    short8 a1 = *(short8*)&lds_a[(arow * 128 + 32 + kq8) ^ ((arow & 7) << 3)];
    short8 a2 = *(short8*)&lds_a[(arow * 128 + 64 + kq8) ^ ((arow & 7) << 3)];
    short8 a3 = *(short8*)&lds_a[(arow * 128 + 96 + kq8) ^ ((arow & 7) << 3)];
#pragma unroll
    for (int f = 0; f < 4; ++f) {
      int c = f * 16 + cbase;
      short8 b0 = *(short8*)&lds_b1[(c * 128 + kq8) ^ ((c & 7) << 3)];
      short8 bb1 = *(short8*)&lds_b1[(c * 128 + 32 + kq8) ^ ((c & 7) << 3)];
      short8 b2v = *(short8*)&lds_b1[(c * 128 + 64 + kq8) ^ ((c & 7) << 3)];
      short8 b3v = *(short8*)&lds_b1[(c * 128 + 96 + kq8) ^ ((c & 7) << 3)];
      acc1[f] = __builtin_amdgcn_mfma_f32_16x16x32_bf16(a0, b0, acc1[f], 0, 0, 0);
      acc1[f] = __builtin_amdgcn_mfma_f32_16x16x32_bf16(a1, bb1, acc1[f], 0, 0, 0);
      acc1[f] = __builtin_amdgcn_mfma_f32_16x16x32_bf16(a2, b2v, acc1[f], 0, 0, 0);
      acc1[f] = __builtin_amdgcn_mfma_f32_16x16x32_bf16(a3, b3v, acc1[f], 0, 0, 0);
    }
  }
  {
    float s[4] = {0, 0, 0, 0}, q[4] = {0, 0, 0, 0};
#pragma unroll
    for (int f = 0; f < 4; ++f) {
      int c = f * 16 + cbase;
      float bias = b1[c];
#pragma unroll
      for (int j = 0; j < 4; ++j) {
        float v = acc1[f][j] + bias;
        acc1[f][j] = v;
        s[j] += v; q[j] += v * v;
      }
    }
#pragma unroll
    for (int off = 8; off >= 1; off >>= 1)
#pragma unroll
      for (int j = 0; j < 4; ++j) {
        s[j] += __shfl_xor(s[j], off);
        q[j] += __shfl_xor(q[j], off);
      }
#pragma unroll
    for (int j = 0; j < 4; ++j) {
      int row = wid * 16 + (lane >> 4) * 4 + j;
      float mu = s[j] * (1.f / 64.f);
      float var = q[j] * (1.f / 64.f) - mu * mu;
      float rs = rsqrtf(var + 1e-5f);
#pragma unroll
      for (int f = 0; f < 4; ++f) {
        int c = f * 16 + cbase;
        float y = fmaxf((acc1[f][j] - mu) * rs * g1[c] + be1[c], 0.f);
        lds_h1[(row * 64 + c) ^ ((row & 7) << 3)] = f2bf(y);
      }
    }
  }
  __syncthreads();

  // ---- stage 2: 64 -> 32 ----
  f32x4 acc2[2];
#pragma unroll
  for (int f = 0; f < 2; ++f)
#pragma unroll
    for (int j = 0; j < 4; ++j) acc2[f][j] = 0.f;
  {
    short8 a0 = *(short8*)&lds_h1[(arow * 64 + kq8) ^ ((arow & 7) << 3)];
    short8 a1 = *(short8*)&lds_h1[(arow * 64 + 32 + kq8) ^ ((arow & 7) << 3)];
#pragma unroll
    for (int f = 0; f < 2; ++f) {
      int c = f * 16 + cbase;
      short8 b0 = *(short8*)&lds_b2[(c * 64 + kq8) ^ ((c & 7) << 3)];
      short8 bb1 = *(short8*)&lds_b2[(c * 64 + 32 + kq8) ^ ((c & 7) << 3)];
      acc2[f] = __builtin_amdgcn_mfma_f32_16x16x32_bf16(a0, b0, acc2[f], 0, 0, 0);
      acc2[f] = __builtin_amdgcn_mfma_f32_16x16x32_bf16(a1, bb1, acc2[f], 0, 0, 0);
    }
  }
  {
    float s[4] = {0, 0, 0, 0}, q[4] = {0, 0, 0, 0};
#pragma unroll
    for (int f = 0; f < 2; ++f) {
      int c = f * 16 + cbase;
      float bias = b2[c];
#pragma unroll
      for (int j = 0; j < 4; ++j) {
        float v = acc2[f][j] + bias;
        acc2[f][j] = v;
        s[j] += v; q[j] += v * v;
      }
    }
#pragma unroll
    for (int off = 8; off >= 1; off >>= 1)
#pragma unroll
      for (int j = 0; j < 4; ++j) {
        s[j] += __shfl_xor(s[j], off);
        q[j] += __shfl_xor(q[j], off);
      }
#pragma unroll
    for (int j = 0; j < 4; ++j) {
      int row = wid * 16 + (lane >> 4) * 4 + j;
      float mu = s[j] * (1.f / 32.f);
      float var = q[j] * (1.f / 32.f) - mu * mu;
      float rs = rsqrtf(var + 1e-5f);
#pragma unroll
      for (int f = 0; f < 2; ++f) {
        int c = f * 16 + cbase;
        float y = fmaxf((acc2[f][j] - mu) * rs * g2[c] + be2[c], 0.f);
        lds_h2[(row * 32 + c) ^ ((row & 3) << 3)] = f2bf(y);
      }
    }
  }
  __syncthreads();

  // ---- stage 3: 32 -> 8 (cols padded to 16) ----
  f32x4 acc3;
#pragma unroll
  for (int j = 0; j < 4; ++j) acc3[j] = 0.f;
  {
    short8 a = *(short8*)&lds_h2[(arow * 32 + kq8) ^ ((arow & 3) << 3)];
    short8 b = *(short8*)&lds_b3[(cbase * 32 + kq8) ^ ((cbase & 3) << 3)];
    acc3 = __builtin_amdgcn_mfma_f32_16x16x32_bf16(a, b, acc3, 0, 0, 0);
  }
  if (cbase < N_CLASSES) {
    float bias = b3[cbase];
#pragma unroll
    for (int j = 0; j < 4; ++j) {
      size_t row = row0 + wid * 16 + (lane >> 4) * 4 + j;
      if (row < N_NODES) out[row * N_CLASSES + cbase] = acc3[j] + bias;
    }
  }
}

// ---------------- launch ----------------
extern "C" void kernel_launch(void* const* d_in, const int* in_sizes, int n_in,
                              void* d_out, int out_size, void* d_ws, size_t ws_size,
                              hipStream_t stream) {
  const float* x     = (const float*)d_in[0];
  const int*   esrc  = (const int*)d_in[1];
  const int*   edst  = (const int*)d_in[2];
  const float* W_in  = (const float*)d_in[3];
  const float* b_in  = (const float*)d_in[4];
  const float* g_in  = (const float*)d_in[5];
  const float* be_in = (const float*)d_in[6];
  const float* Wc    = (const float*)d_in[7];
  const float* a_src = (const float*)d_in[8];
  const float* a_dst = (const float*)d_in[9];
  const float* bc    = (const float*)d_in[10];
  const float* gc    = (const float*)d_in[11];
  const float* bec   = (const float*)d_in[12];
  const float* W1    = (const float*)d_in[13];
  const float* b1    = (const float*)d_in[14];
  const float* g1    = (const float*)d_in[15];
  const float* be1   = (const float*)d_in[16];
  const float* W2    = (const float*)d_in[17];
  const float* b2    = (const float*)d_in[18];
  const float* g2    = (const float*)d_in[19];
  const float* be2   = (const float*)d_in[20];
  const float* W3    = (const float*)d_in[21];
  const float* b3    = (const float*)d_in[22];

  const size_t NH = (size_t)N_NODES * HID;
  unsigned short* hA = (unsigned short*)d_ws;     // bf16 [N][128]
  unsigned short* hB = hA + NH;
  unsigned short* hp_bf = hB + NH;
  float* es = (float*)(hp_bf + NH);
  float* ed = es + (size_t)N_NODES * HEADS;
  int* deg    = (int*)(ed + (size_t)N_NODES * HEADS);
  int* cur    = deg + N_NODES;
  int* startv = cur + N_NODES;
  int* blocksum  = startv + N_NODES;
  int* blockoffs = blocksum + NBLK;
  int* col    = blockoffs + NBLK;
  uintptr_t wp = (uintptr_t)(col + N_EDGES);
  wp = (wp + 15) & ~(uintptr_t)15;
  unsigned short* Wt_in = (unsigned short*)wp;
  unsigned short* Wt_c  = Wt_in + (size_t)IN_DIM * HID;
  unsigned short* W1t   = Wt_c + (size_t)N_LAYERS * HID * HID;
  unsigned short* W2t   = W1t + 64 * 128;
  unsigned short* W3t   = W2t + 32 * 64;

  // weights -> bf16 transposed + zero deg/cur (merged)
  k_prep<<<(2 * N_NODES + 255) / 256, 256, 0, stream>>>(
      W_in, Wc, W1, W2, W3, Wt_in, Wt_c, W1t, W2t, W3t, deg);

  // input projection + LN + relu (MFMA) -> bf16 h
  k_gemm_in<<<(N_NODES + 63) / 64, 256, 0, stream>>>(x, Wt_in, b_in, g_in, be_in, hA);

  // CSR build: count -> hierarchical scan -> scatter
  k_count<<<(N_EDGES + 255) / 256, 256, 0, stream>>>(edst, deg);
  k_scan_local<<<NBLK, 256, 0, stream>>>(deg, startv, blocksum);
  k_scan_block<<<1, 256, 0, stream>>>(blocksum, blockoffs);
  k_scan_add<<<NBLK, 256, 0, stream>>>(startv, blockoffs);
  k_scatter<<<(N_EDGES + 255) / 256, 256, 0, stream>>>(esrc, edst, startv, cur, col);

  unsigned short* hcur = hA;
  unsigned short* hnext = hB;
  for (int l = 0; l < N_LAYERS; ++l) {
    k_gemm_gat<<<(N_NODES + 63) / 64, 256, 0, stream>>>(
        hcur, Wt_c + (size_t)l * HID * HID,
        a_src + (size_t)l * HEADS * HEAD_DIM, a_dst + (size_t)l * HEADS * HEAD_DIM,
        hp_bf, es, ed);
    k_gat_agg<<<(N_NODES + 3) / 4, 256, 0, stream>>>(
        hp_bf, es, ed, startv, deg, col,
        bc + (size_t)l * HID, gc + (size_t)l * HID, bec + (size_t)l * HID,
        (const unsigned*)hcur, (unsigned*)hnext, l > 0 ? 1 : 0);
    unsigned short* t = hcur; hcur = hnext; hnext = t;
  }

  k_head_mfma<<<(N_NODES + 63) / 64, 256, 0, stream>>>(
      hcur, W1t, b1, g1, be1, W2t, b2, g2, be2, W3t, b3, (float*)d_out);
}